// Round 9
// baseline (5157.054 us; speedup 1.0000x reference)
//
#include <hip/hip_runtime.h>
#include <math.h>

#define BSZ 256
#define NV  4096
#define MC  2048
#define HID 1024
#define FREEN 512
#define NITER 31
#define TOLF 1e-4f
#define EPSF 1e-6f
#define INV2048 4.8828125e-4f

typedef _Float16 half8 __attribute__((ext_vector_type(8)));
typedef _Float16 half4 __attribute__((ext_vector_type(4)));
typedef float f32x16 __attribute__((ext_vector_type(16)));

enum { EPI_NONE=0, EPI_BIASRELU=1, EPI_BIAS=2, EPI_ADDMAT=3, EPI_EQ=4, EPI_SUBMAT=5 };

// packed tile layout: [row-tile 128][k-tile 32] -> 4096-elem tile, k-octet-major:
// off = tile*4096 + oct*1024 + (row&127)*8 + (k&7)
__device__ __forceinline__ size_t pidx(int row, int k, int Kdim){
  return ((size_t)((row>>7)*(Kdim>>5) + (k>>5)))*4096
       + (size_t)(((k>>3)&3)*1024 + (row&127)*8 + (k&7));
}

// ---------------- f32 vector-ALU GEMM (fallback path only) ----------------
template<int BM,int BN,int BK,int TM,int TN,bool TB,bool RELUIN,int EPI>
__global__ __launch_bounds__(256)
void gemm_k(const float* __restrict__ X, int ldx,
            const float* __restrict__ W, int ldw,
            float* __restrict__ C,
            int K, int N,
            const float* __restrict__ bvec,
            const float* __restrict__ addm, int ldadd,
            const int* __restrict__ guard)
{
  if (guard && guard[0]) return;
  const int t = (int)threadIdx.x;
  const int m0 = (int)blockIdx.y*BM, n0 = (int)blockIdx.x*BN;
  __shared__ float As[BK][BM+4];
  __shared__ float Bs[BK][BN+4];
  constexpr int TX = BN/TN;
  const int tx = t % TX, ty = t / TX;
  constexpr int ALD = (BM*BK)/1024;
  constexpr int BLD = (BN*BK)/1024;
  float4 pa[ALD], pb[BLD];
  float acc[TM][TN];
  #pragma unroll
  for (int i=0;i<TM;i++)
    #pragma unroll
    for (int j=0;j<TN;j++) acc[i][j]=0.f;

  const int nk = K/BK;

  auto loadA = [&](int kt){
    const int k0 = kt*BK;
    const bool rl = RELUIN && (k0 >= FREEN);
    #pragma unroll
    for (int q=0;q<ALD;q++){
      const int idx = q*256 + t;
      const int r = idx/(BK/4), c4 = (idx%(BK/4))*4;
      float4 v = *reinterpret_cast<const float4*>(&X[(size_t)(m0+r)*ldx + k0 + c4]);
      if (rl){ v.x=fmaxf(v.x,0.f); v.y=fmaxf(v.y,0.f); v.z=fmaxf(v.z,0.f); v.w=fmaxf(v.w,0.f); }
      pa[q]=v;
    }
  };
  auto loadB = [&](int kt){
    const int k0 = kt*BK;
    #pragma unroll
    for (int q=0;q<BLD;q++){
      const int idx = q*256 + t;
      if (TB){
        const int r = idx/(BK/4), c4 = (idx%(BK/4))*4;
        pb[q] = *reinterpret_cast<const float4*>(&W[(size_t)(n0+r)*ldw + k0 + c4]);
      } else {
        const int r = idx/(BN/4), c4 = (idx%(BN/4))*4;
        pb[q] = *reinterpret_cast<const float4*>(&W[(size_t)(k0+r)*ldw + n0 + c4]);
      }
    }
  };
  auto stor = [&](){
    #pragma unroll
    for (int q=0;q<ALD;q++){
      const int idx = q*256 + t;
      const int r = idx/(BK/4), c4 = (idx%(BK/4))*4;
      As[c4+0][r]=pa[q].x; As[c4+1][r]=pa[q].y; As[c4+2][r]=pa[q].z; As[c4+3][r]=pa[q].w;
    }
    #pragma unroll
    for (int q=0;q<BLD;q++){
      const int idx = q*256 + t;
      if (TB){
        const int r = idx/(BK/4), c4 = (idx%(BK/4))*4;
        Bs[c4+0][r]=pb[q].x; Bs[c4+1][r]=pb[q].y; Bs[c4+2][r]=pb[q].z; Bs[c4+3][r]=pb[q].w;
      } else {
        const int r = idx/(BN/4), c4 = (idx%(BN/4))*4;
        *reinterpret_cast<float4*>(&Bs[r][c4]) = pb[q];
      }
    }
  };

  loadA(0); loadB(0);
  for (int kt=0; kt<nk; ++kt){
    __syncthreads();
    stor();
    __syncthreads();
    if (kt+1 < nk){ loadA(kt+1); loadB(kt+1); }
    #pragma unroll
    for (int kk=0; kk<BK; ++kk){
      float a[TM], b[TN];
      if constexpr (TM==4) *reinterpret_cast<float4*>(a) = *reinterpret_cast<const float4*>(&As[kk][ty*TM]);
      else                 *reinterpret_cast<float2*>(a) = *reinterpret_cast<const float2*>(&As[kk][ty*TM]);
      if constexpr (TN==4) *reinterpret_cast<float4*>(b) = *reinterpret_cast<const float4*>(&Bs[kk][tx*TN]);
      else                 *reinterpret_cast<float2*>(b) = *reinterpret_cast<const float2*>(&Bs[kk][tx*TN]);
      #pragma unroll
      for (int i=0;i<TM;i++)
        #pragma unroll
        for (int j=0;j<TN;j++)
          acc[i][j] = fmaf(a[i], b[j], acc[i][j]);
    }
  }

  if constexpr (EPI==EPI_EQ){
    float csum[TN];
    #pragma unroll
    for (int j=0;j<TN;j++) csum[j]=0.f;
    #pragma unroll
    for (int i=0;i<TM;i++){
      const int r = m0 + ty*TM + i;
      #pragma unroll
      for (int j=0;j<TN;j++){
        const int c = n0 + tx*TN + j;
        const float v = acc[i][j] - addm[(size_t)r*ldadd + c];
        csum[j] += fabsf(v);
      }
    }
    __syncthreads();
    float* red = &As[0][0];
    constexpr int RY = BM/TM;
    #pragma unroll
    for (int j=0;j<TN;j++) red[(tx*TN+j)*RY + ty] = csum[j];
    __syncthreads();
    if (t < BN){
      float s=0.f;
      #pragma unroll
      for (int y=0;y<RY;y++) s += red[t*RY + y];
      C[(size_t)blockIdx.y*N + n0 + t] = s;
    }
  } else {
    #pragma unroll
    for (int i=0;i<TM;i++){
      const int r = m0 + ty*TM + i;
      #pragma unroll
      for (int j=0;j<TN;j++){
        const int c = n0 + tx*TN + j;
        float v = acc[i][j];
        if constexpr (EPI==EPI_BIASRELU){ v += bvec[c]; v = fmaxf(v,0.f); }
        if constexpr (EPI==EPI_BIAS)    { v += bvec[c]; }
        if constexpr (EPI==EPI_ADDMAT)  { v += addm[(size_t)r*ldadd + c]; }
        if constexpr (EPI==EPI_SUBMAT)  { v -= addm[(size_t)r*ldadd + c]; }
        C[(size_t)r*N + c] = v;
      }
    }
  }
}

// ---------------- fp16x2 split helpers ----------------
__device__ __forceinline__ void split_f32(float v, _Float16& h, _Float16& l){
  float hf = 0.f;
  _Float16 hh = (_Float16)0.f;
  if (fabsf(v) >= 6.103515625e-05f) { hh = (_Float16)v; hf = (float)hh; }
  h = hh;
  l = (_Float16)((v - hf) * 2048.0f);
}

__global__ __launch_bounds__(256)
void split_k(const float* __restrict__ src, _Float16* __restrict__ h,
             _Float16* __restrict__ l, int n4)
{
  const int i = blockIdx.x*256 + threadIdx.x;
  if (i >= n4) return;
  const float4 v = *reinterpret_cast<const float4*>(&src[(size_t)i*4]);
  half4 hh, ll;
  _Float16 a, b;
  split_f32(v.x,a,b); hh.x=a; ll.x=b;
  split_f32(v.y,a,b); hh.y=a; ll.y=b;
  split_f32(v.z,a,b); hh.z=a; ll.z=b;
  split_f32(v.w,a,b); hh.w=a; ll.w=b;
  *reinterpret_cast<half4*>(&h[(size_t)i*4]) = hh;
  *reinterpret_cast<half4*>(&l[(size_t)i*4]) = ll;
}

// split + PACK: src f32 [R][K] -> packed fp16 pair. thread = one k-octet.
__global__ __launch_bounds__(256)
void splitpack_k(const float* __restrict__ src, _Float16* __restrict__ oh,
                 _Float16* __restrict__ ol, int R, int K)
{
  const long long o = (long long)blockIdx.x*256 + threadIdx.x;
  if (o >= (long long)R*(K>>3)) return;
  const int row = (int)(o / (K>>3));
  const int k   = ((int)(o % (K>>3)))*8;
  const float4 v0 = *reinterpret_cast<const float4*>(&src[(size_t)row*K + k]);
  const float4 v1 = *reinterpret_cast<const float4*>(&src[(size_t)row*K + k + 4]);
  half8 hh, ll;
  _Float16 a, b;
  split_f32(v0.x,a,b); hh[0]=a; ll[0]=b;
  split_f32(v0.y,a,b); hh[1]=a; ll[1]=b;
  split_f32(v0.z,a,b); hh[2]=a; ll[2]=b;
  split_f32(v0.w,a,b); hh[3]=a; ll[3]=b;
  split_f32(v1.x,a,b); hh[4]=a; ll[4]=b;
  split_f32(v1.y,a,b); hh[5]=a; ll[5]=b;
  split_f32(v1.z,a,b); hh[6]=a; ll[6]=b;
  split_f32(v1.w,a,b); hh[7]=a; ll[7]=b;
  const size_t po = pidx(row, k, K);
  *reinterpret_cast<half8*>(&oh[po]) = hh;
  if (ol) *reinterpret_cast<half8*>(&ol[po]) = ll;
}

// transpose-convert+PACK: W [NV][MC] f32 -> Wt packed [MC rows][NV k] fp16 hi-only
__global__ __launch_bounds__(256)
void trsplit_k(const float* __restrict__ W, _Float16* __restrict__ Wt)
{
  __shared__ float ts[64][65];
  const int t = (int)threadIdx.x;
  const int i0 = (int)blockIdx.x*64;   // k range (W rows)
  const int j0 = (int)blockIdx.y*64;   // out rows (W cols)
  const int rr = t >> 4, cc = (t & 15)*4;
  #pragma unroll
  for (int p=0;p<4;p++){
    const int r = p*16 + rr;
    const float4 v = *reinterpret_cast<const float4*>(&W[(size_t)(i0+r)*MC + j0 + cc]);
    ts[r][cc+0]=v.x; ts[r][cc+1]=v.y; ts[r][cc+2]=v.z; ts[r][cc+3]=v.w;
  }
  __syncthreads();
  // write half8 per thread: 32 out-rows x 8 octet-cols per pass
  const int orow_h = t >> 3, c8 = (t & 7)*8;
  #pragma unroll
  for (int p=0;p<2;p++){
    const int orow = p*32 + orow_h;
    half8 h8;
    #pragma unroll
    for (int e=0;e<8;e++) h8[e] = (_Float16)ts[c8+e][orow];
    *reinterpret_cast<half8*>(&Wt[pidx(j0+orow, i0+c8, NV)]) = h8;
  }
}

// transpose + pair-split (linear out, prologue): W [R][C] f32 -> out [C][R] fp16 pair
__global__ __launch_bounds__(256)
void trsplit2_k(const float* __restrict__ W, _Float16* __restrict__ oh,
                _Float16* __restrict__ ol, int R, int C)
{
  __shared__ float ts[64][65];
  const int t = (int)threadIdx.x;
  const int i0 = (int)blockIdx.x*64;
  const int j0 = (int)blockIdx.y*64;
  const int rr = t >> 4, cc = (t & 15)*4;
  #pragma unroll
  for (int p=0;p<4;p++){
    const int r = p*16 + rr;
    const float4 v = *reinterpret_cast<const float4*>(&W[(size_t)(i0+r)*C + j0 + cc]);
    ts[r][cc+0]=v.x; ts[r][cc+1]=v.y; ts[r][cc+2]=v.z; ts[r][cc+3]=v.w;
  }
  __syncthreads();
  #pragma unroll
  for (int p=0;p<4;p++){
    const int orow = p*16 + rr;
    half4 h4, l4;
    _Float16 h, l;
    split_f32(ts[cc+0][orow], h, l); h4.x=h; l4.x=l;
    split_f32(ts[cc+1][orow], h, l); h4.y=h; l4.y=l;
    split_f32(ts[cc+2][orow], h, l); h4.z=h; l4.z=l;
    split_f32(ts[cc+3][orow], h, l); h4.w=h; l4.w=l;
    const size_t o = (size_t)(j0+orow)*R + i0 + cc;
    *reinterpret_cast<half4*>(&oh[o]) = h4;
    *reinterpret_cast<half4*>(&ol[o]) = l4;
  }
}

// ---------------- generic fp16x2 pair-GEMM (prologue, linear operands) ----------------
__global__ __launch_bounds__(256)
void pairgemm_k(const _Float16* __restrict__ Ahg, const _Float16* __restrict__ Alg,
                const _Float16* __restrict__ Bhg, const _Float16* __restrict__ Blg,
                float* __restrict__ partial, int N, int K, int kzn,
                const int* __restrict__ guard)
{
  if (guard[0]) return;
  __shared__ _Float16 lds[2][8192];
  const int t = (int)threadIdx.x;
  const int lane = t & 63, wid = t >> 6;
  const int wr = wid >> 1, wc = wid & 1;
  const int ln = lane & 31, lg = lane >> 5;

  const int nt = (int)blockIdx.x, mt = (int)blockIdx.y, kz = (int)blockIdx.z;
  const int m0 = mt*128, n0 = nt*128;
  const int chunk = (3*K)/kzn;
  const int loExt = kz*chunk;
  const int nsteps = chunk/32;
  int ss = (2*K - loExt)/32;
  const int scaleStep = ss < 0 ? 0 : ss;

  f32x16 acc[2][2];
  #pragma unroll
  for (int fm=0;fm<2;fm++)
    #pragma unroll
    for (int fn=0;fn<2;fn++)
      #pragma unroll
      for (int r=0;r<16;r++) acc[fm][fn][r] = 0.f;

  auto stage = [&](int i, int buf){
    const int gext = loExt + i*32;
    const _Float16* aB; const _Float16* bB; int kk;
    if (gext < K)         { aB = Ahg; bB = Blg; kk = gext; }
    else if (gext < 2*K)  { aB = Alg; bB = Bhg; kk = gext - K; }
    else                  { aB = Ahg; bB = Bhg; kk = gext - 2*K; }
    _Float16* base = &lds[buf][0];
    #pragma unroll
    for (int q=0;q<2;q++){
      const int W = q*4 + wid;
      const int co = (W>>1)*8;
      const int rw = (W&1)*64 + lane;
      const _Float16* ga = aB + (size_t)(m0 + rw)*K + kk + co;
      __builtin_amdgcn_global_load_lds(
        (const __attribute__((address_space(1))) void*)ga,
        (__attribute__((address_space(3))) void*)(base + W*512), 16, 0, 0);
      const _Float16* gb = bB + (size_t)(n0 + rw)*K + kk + co;
      __builtin_amdgcn_global_load_lds(
        (const __attribute__((address_space(1))) void*)gb,
        (__attribute__((address_space(3))) void*)(base + 4096 + W*512), 16, 0, 0);
    }
  };

  int cur = 0;
  stage(0, 0);
  __syncthreads();
  for (int i=0; i<nsteps; ++i){
    if (i+1 < nsteps) stage(i+1, cur^1);
    const _Float16* As = &lds[cur][0];
    const _Float16* Bs = &lds[cur][4096];
    half8 a[2][2], b[2][2];
    #pragma unroll
    for (int fm=0; fm<2; ++fm){
      const int row = wr*64 + fm*32 + ln;
      #pragma unroll
      for (int ks=0; ks<2; ++ks)
        a[fm][ks] = *reinterpret_cast<const half8*>(&As[(ks*2+lg)*1024 + row*8]);
    }
    #pragma unroll
    for (int fn=0; fn<2; ++fn){
      const int row = wc*64 + fn*32 + ln;
      #pragma unroll
      for (int ks=0; ks<2; ++ks)
        b[fn][ks] = *reinterpret_cast<const half8*>(&Bs[(ks*2+lg)*1024 + row*8]);
    }
    if (i == scaleStep){
      #pragma unroll
      for (int fm=0;fm<2;fm++)
        #pragma unroll
        for (int fn=0;fn<2;fn++)
          #pragma unroll
          for (int r=0;r<16;r++) acc[fm][fn][r] *= INV2048;
    }
    #pragma unroll
    for (int ks=0; ks<2; ++ks)
      #pragma unroll
      for (int fm=0; fm<2; ++fm)
        #pragma unroll
        for (int fn=0; fn<2; ++fn)
          acc[fm][fn] = __builtin_amdgcn_mfma_f32_32x32x16_f16(a[fm][ks], b[fn][ks], acc[fm][fn], 0, 0, 0);
    __syncthreads();
    cur ^= 1;
  }
  if (scaleStep >= nsteps){
    #pragma unroll
    for (int fm=0;fm<2;fm++)
      #pragma unroll
      for (int fn=0;fn<2;fn++)
        #pragma unroll
        for (int r=0;r<16;r++) acc[fm][fn][r] *= INV2048;
  }

  float* __restrict__ dst = partial + (size_t)kz*BSZ*N;
  #pragma unroll
  for (int fm=0; fm<2; ++fm)
    #pragma unroll
    for (int fn=0; fn<2; ++fn)
      #pragma unroll
      for (int r=0; r<16; ++r){
        const int row = (r&3) + 8*(r>>2) + 4*lg;
        const int gm = m0 + wr*64 + fm*32 + row;
        const int gn = n0 + wc*64 + fn*32 + ln;
        dst[(size_t)gm*N + gn] = acc[fm][fn][r];
      }
}

// NOTE: pairgemm's LDS k-octet reads expect the round-8 window layout; its operands
// are linear [rows][K], staged with the (W>>1) octet / (W&1) row-half windows above.

// sum of kz partials + flexible epilogue. grid (N/256, 16). packed: pair in packed layout.
__global__ __launch_bounds__(256)
void sumn_k(const float* __restrict__ partial, int ng, int N,
            const float* __restrict__ bvec, const float* __restrict__ subm,
            int relu, int packed, float* __restrict__ outf,
            _Float16* __restrict__ oh, _Float16* __restrict__ ol,
            const int* __restrict__ guard)
{
  if (guard[0]) return;
  const int c = blockIdx.x*256 + threadIdx.x;
  const int rb = blockIdx.y;
  const size_t SZ = (size_t)BSZ*N;
  for (int r=0; r<16; ++r){
    const int row = rb*16+r;
    const size_t idx = (size_t)row*N + c;
    float s = 0.f;
    for (int g=0; g<ng; ++g) s += partial[(size_t)g*SZ + idx];
    if (bvec) s += bvec[c];
    if (subm) s -= subm[idx];
    if (relu) s = fmaxf(s, 0.f);
    outf[idx] = s;
    if (oh){
      _Float16 h, l; split_f32(s, h, l);
      const size_t o = packed ? pidx(row, c, N) : idx;
      oh[o] = h; ol[o] = l;
    }
  }
}

// ---------------- fused loop MFMA kernel (packed operands, XCD swizzle) ----------------
__global__ __launch_bounds__(256)
void fusedm_k(const _Float16* __restrict__ Ahg, const _Float16* __restrict__ Alg,
              const _Float16* __restrict__ Wzh, const _Float16* __restrict__ Wzl,
              const _Float16* __restrict__ Wbt,
              float* __restrict__ pp, float* __restrict__ ppe,
              int projKz, int eqKz, const int* __restrict__ guard)
{
  if (guard[0]) return;
  __shared__ _Float16 lds[2][8192];
  const int t = (int)threadIdx.x;
  const int lane = t & 63, wid = t >> 6;
  const int wr = wid >> 1, wc = wid & 1;
  const int ln = lane & 31, lg = lane >> 5;

  // XCD-bijective swizzle: consecutive logical ids share an XCD's L2
  const int nwg = (int)gridDim.x;
  const int hw = (int)blockIdx.x;
  const int L = (hw & 7)*(nwg >> 3) + (hw >> 3);

  const int nProj = 64*projKz;
  const bool is_eq = L >= nProj;
  int kz, mt, nt, nsteps, scaleStep, loExt, chunk;
  if (!is_eq){
    mt = L & 1;
    kz = (L >> 1) % projKz;
    nt = L / (2*projKz);
    chunk = 12288 / projKz;
    loExt = kz * chunk;
    nsteps = chunk / 32;
    const int ss = (8192 - loExt) / 32;
    scaleStep = ss < 0 ? 0 : ss;
  } else {
    const int E = L - nProj;
    mt = E & 1;
    kz = (E >> 1) % eqKz;
    nt = E / (2*eqKz);
    chunk = 0; loExt = 0;
    nsteps = (NV/eqKz) / 32;
    scaleStep = -1;
  }
  const int m0 = mt*128, n0 = nt*128;

  f32x16 acc[2][2];
  #pragma unroll
  for (int fm=0;fm<2;fm++)
    #pragma unroll
    for (int fn=0;fn<2;fn++)
      #pragma unroll
      for (int r=0;r<16;r++) acc[fm][fn][r] = 0.f;

  auto stage = [&](int i, int buf){
    const _Float16* aB; const _Float16* bB; int kk;
    if (is_eq){
      aB = Ahg; bB = Wbt; kk = kz*(NV/eqKz) + i*32;
    } else {
      const int gext = loExt + i*32;
      if (gext < 4096)      { aB = Ahg; bB = Wzl; kk = gext; }
      else if (gext < 8192) { aB = Alg; bB = Wzh; kk = gext - 4096; }
      else                  { aB = Ahg; bB = Wzh; kk = gext - 8192; }
    }
    const int kt = kk >> 5;
    const _Float16* aT = aB + ((size_t)(mt*128 + kt))*4096;          // A rows 256 -> rt=mt
    const _Float16* bT = bB + ((size_t)((n0>>7)*128 + kt))*4096;     // B K=4096 -> 128 ktiles
    _Float16* base = &lds[buf][0];
    #pragma unroll
    for (int q=0;q<2;q++){
      const int W = q*4 + wid;
      __builtin_amdgcn_global_load_lds(
        (const __attribute__((address_space(1))) void*)(aT + W*512 + lane*8),
        (__attribute__((address_space(3))) void*)(base + W*512), 16, 0, 0);
      __builtin_amdgcn_global_load_lds(
        (const __attribute__((address_space(1))) void*)(bT + W*512 + lane*8),
        (__attribute__((address_space(3))) void*)(base + 4096 + W*512), 16, 0, 0);
    }
  };

  int cur = 0;
  stage(0, 0);
  __syncthreads();
  for (int i=0; i<nsteps; ++i){
    if (i+1 < nsteps) stage(i+1, cur^1);
    const _Float16* As = &lds[cur][0];
    const _Float16* Bs = &lds[cur][4096];
    half8 a[2][2], b[2][2];
    #pragma unroll
    for (int fm=0; fm<2; ++fm){
      const int row = wr*64 + fm*32 + ln;
      #pragma unroll
      for (int ks=0; ks<2; ++ks)
        a[fm][ks] = *reinterpret_cast<const half8*>(&As[(ks*2+lg)*1024 + row*8]);
    }
    #pragma unroll
    for (int fn=0; fn<2; ++fn){
      const int row = wc*64 + fn*32 + ln;
      #pragma unroll
      for (int ks=0; ks<2; ++ks)
        b[fn][ks] = *reinterpret_cast<const half8*>(&Bs[(ks*2+lg)*1024 + row*8]);
    }
    if (!is_eq && i == scaleStep){
      #pragma unroll
      for (int fm=0;fm<2;fm++)
        #pragma unroll
        for (int fn=0;fn<2;fn++)
          #pragma unroll
          for (int r=0;r<16;r++) acc[fm][fn][r] *= INV2048;
    }
    #pragma unroll
    for (int ks=0; ks<2; ++ks)
      #pragma unroll
      for (int fm=0; fm<2; ++fm)
        #pragma unroll
        for (int fn=0; fn<2; ++fn)
          acc[fm][fn] = __builtin_amdgcn_mfma_f32_32x32x16_f16(a[fm][ks], b[fn][ks], acc[fm][fn], 0, 0, 0);
    __syncthreads();
    cur ^= 1;
  }
  if (!is_eq && scaleStep >= nsteps){
    #pragma unroll
    for (int fm=0;fm<2;fm++)
      #pragma unroll
      for (int fn=0;fn<2;fn++)
        #pragma unroll
        for (int r=0;r<16;r++) acc[fm][fn][r] *= INV2048;
  }

  if (is_eq){
    float* __restrict__ dst = ppe + (size_t)kz*BSZ*MC;
    #pragma unroll
    for (int fm=0; fm<2; ++fm)
      #pragma unroll
      for (int fn=0; fn<2; ++fn)
        #pragma unroll
        for (int r=0; r<16; ++r){
          const int row = (r&3) + 8*(r>>2) + 4*lg;
          const int gm = m0 + wr*64 + fm*32 + row;
          const int gn = n0 + wc*64 + fn*32 + ln;
          dst[(size_t)gm*MC + gn] = acc[fm][fn][r];
        }
  } else {
    float* __restrict__ dst = pp + (size_t)kz*BSZ*NV;
    #pragma unroll
    for (int fm=0; fm<2; ++fm)
      #pragma unroll
      for (int fn=0; fn<2; ++fn)
        #pragma unroll
        for (int r=0; r<16; ++r){
          const int row = (r&3) + 8*(r>>2) + 4*lg;
          const int gm = m0 + wr*64 + fm*32 + row;
          const int gn = n0 + wc*64 + fn*32 + ln;
          dst[(size_t)gm*NV + gn] = acc[fm][fn][r];
        }
  }
}

// combine: z = sum_ng(pp) + Bias -> z f32, rz pair = split(P2(z)) PACKED, ineq partials
__global__ __launch_bounds__(256)
void combineN_k(const float* __restrict__ pp, const float* __restrict__ BiasM,
                float* __restrict__ zout, _Float16* __restrict__ rzh,
                _Float16* __restrict__ rzl, float* __restrict__ ineqpart,
                int ng, const int* __restrict__ guard)
{
  if (guard[0]) return;
  const int c = blockIdx.x*256 + threadIdx.x;
  const int rb = blockIdx.y;
  const size_t SZ = (size_t)BSZ*NV;
  float acc = 0.f;
  for (int r=0; r<16; ++r){
    const int row = rb*16+r;
    const size_t idx = (size_t)row*NV + c;
    float z = BiasM[idx];
    for (int g=0; g<ng; ++g) z += pp[(size_t)g*SZ + idx];
    zout[idx] = z;
    const float rz = (c >= FREEN) ? fmaxf(z, 0.f) : z;
    _Float16 h, l; split_f32(rz, h, l);
    const size_t o = pidx(row, c, NV);
    rzh[o] = h; rzl[o] = l;
    acc += fmaxf(-z, 0.f);
  }
  ineqpart[(size_t)rb*NV + c] = acc;
}

__global__ __launch_bounds__(256)
void eqredN_k(const float* __restrict__ ppe, const float* __restrict__ BiasATmB,
              float* __restrict__ eqpart16, int ng, const int* __restrict__ guard)
{
  if (guard[0]) return;
  const int c = blockIdx.x*256 + threadIdx.x;
  const int rb = blockIdx.y;
  const size_t SE = (size_t)BSZ*MC;
  float s = 0.f;
  for (int r=0; r<16; ++r){
    const size_t idx = (size_t)(rb*16+r)*MC + c;
    float acc = 0.f;
    for (int g=0; g<ng; ++g) acc += ppe[(size_t)g*SE + idx];
    s += fabsf(BiasATmB[idx] + EPSF*acc);
  }
  eqpart16[(size_t)rb*MC + c] = s;
}

__global__ __launch_bounds__(256)
void check3_k(const float* __restrict__ eqpart16, const float* __restrict__ ineqpart,
              int* __restrict__ viol, const int* __restrict__ done)
{
  if (done[0]) return;
  const int id = blockIdx.x*256 + threadIdx.x;
  bool bad;
  if (id < MC){
    float s = 0.f;
    #pragma unroll
    for (int g=0; g<16; g++) s += eqpart16[(size_t)g*MC + id];
    bad = (s*(1.f/(float)BSZ) > TOLF);
  } else {
    const int c = FREEN + (id - MC);
    float s = 0.f;
    #pragma unroll
    for (int g=0; g<16; g++) s += ineqpart[(size_t)g*NV + c];
    bad = (s*(1.f/(float)BSZ) > TOLF);
  }
  if (bad) atomicAdd(viol, 1);
}

// ---------------- LayerNorm ----------------
__global__ __launch_bounds__(256)
void ln_k(float* __restrict__ x, const float* __restrict__ g, const float* __restrict__ b)
{
  const int row = blockIdx.x, t = threadIdx.x;
  float4 v = *reinterpret_cast<const float4*>(&x[(size_t)row*HID + t*4]);
  __shared__ float sm[256];
  sm[t] = v.x+v.y+v.z+v.w;
  __syncthreads();
  for (int st=128; st>0; st>>=1){ if (t<st) sm[t]+=sm[t+st]; __syncthreads(); }
  const float mu = sm[0]*(1.f/(float)HID);
  __syncthreads();
  const float dx=v.x-mu, dy=v.y-mu, dz=v.z-mu, dw=v.w-mu;
  sm[t] = dx*dx+dy*dy+dz*dz+dw*dw;
  __syncthreads();
  for (int st=128; st>0; st>>=1){ if (t<st) sm[t]+=sm[t+st]; __syncthreads(); }
  const float inv = 1.f/sqrtf(sm[0]*(1.f/(float)HID) + 1e-5f);
  const int c = t*4;
  const float4 gv = *reinterpret_cast<const float4*>(&g[c]);
  const float4 bv = *reinterpret_cast<const float4*>(&b[c]);
  float4 o;
  o.x = dx*inv*gv.x + bv.x; o.y = dy*inv*gv.y + bv.y;
  o.z = dz*inv*gv.z + bv.z; o.w = dw*inv*gv.w + bv.w;
  *reinterpret_cast<float4*>(&x[(size_t)row*HID + c]) = o;
}

// ---------------- flags / fallback machinery ----------------
__global__ __launch_bounds__(256)
void check_k(const float* __restrict__ eqpart, const float* __restrict__ znew,
             int* __restrict__ viol, const int* __restrict__ done, int ngroups)
{
  if (done[0]) return;
  const int id = blockIdx.x*256 + threadIdx.x;
  bool bad;
  if (id < MC){
    float s = 0.f;
    for (int g=0; g<ngroups; g++) s += eqpart[g*MC + id];
    bad = (s*(1.f/(float)BSZ) > TOLF);
  } else {
    const int c = FREEN + (id - MC);
    float s = 0.f;
    for (int r=0; r<BSZ; r++){
      const float v = znew[(size_t)r*NV + c];
      s += (v < 0.f) ? -v : 0.f;
    }
    bad = (s*(1.f/(float)BSZ) > TOLF);
  }
  if (bad) atomicAdd(viol, 1);
}

__global__ void init_k(int* flags){ flags[0]=0; flags[1]=0; flags[2]=0; }

__global__ void update_k(int* flags){
  if (!flags[0]){ flags[1] += 1; if (flags[2]==0) flags[0]=1; }
  flags[2] = 0;
}

__global__ __launch_bounds__(256)
void final_k(const float* __restrict__ buf1, float* __restrict__ out, const int* __restrict__ flags)
{
  const int i = blockIdx.x*256 + threadIdx.x;
  const int k = flags[1];
  if ((k & 1) && i < BSZ*NV) out[i] = buf1[i];
  if (i == 0) out[2*BSZ*NV] = (float)k;
}

__global__ void finalp_k(float* __restrict__ out, const int* __restrict__ flags)
{
  out[2*(size_t)BSZ*NV] = (float)flags[1];
}

// ---------------- host launch ----------------
extern "C" void kernel_launch(void* const* d_in, const int* in_sizes, int n_in,
                              void* d_out, int out_size, void* d_ws, size_t ws_size,
                              hipStream_t stream)
{
  const float* bp  = (const float*)d_in[0];
  const float* w1  = (const float*)d_in[1];
  const float* b1  = (const float*)d_in[2];
  const float* g1  = (const float*)d_in[3];
  const float* be1 = (const float*)d_in[4];
  const float* w2  = (const float*)d_in[5];
  const float* b2  = (const float*)d_in[6];
  const float* g2  = (const float*)d_in[7];
  const float* be2 = (const float*)d_in[8];
  const float* w3  = (const float*)d_in[9];
  const float* b3  = (const float*)d_in[10];
  const float* g3  = (const float*)d_in[11];
  const float* be3 = (const float*)d_in[12];
  const float* wo  = (const float*)d_in[13];
  const float* bo  = (const float*)d_in[14];
  const float* A   = (const float*)d_in[15];
  const float* Wz  = (const float*)d_in[16];
  const float* Wb  = (const float*)d_in[17];

  float* out  = (float*)d_out;
  float* z0   = out + (size_t)BSZ*NV;
  float* zbuf = out;

  // choose kz config by ws budget
  auto layout_need = [&](int PKZ, int EKZ)->size_t{
    size_t f = (size_t)1048576*(1+PKZ) + (size_t)524288*(EKZ+1) + 32768 + 65536 + 4;
    size_t hlf = (size_t)NV*NV*2 + (size_t)MC*NV + 2*(size_t)BSZ*NV;
    return f*4 + hlf*2;
  };
  int PKZ = 12, EKZ = 4;
  if (ws_size < layout_need(12,4)) { PKZ = 6; EKZ = 2; }
  const bool fp16path = (ws_size >= layout_need(PKZ, EKZ));

  float* ws_f = (float*)d_ws;
  float* BiasM    = ws_f;
  float* pp       = BiasM + (size_t)BSZ*NV;
  float* ppe      = pp + (size_t)PKZ*BSZ*NV;
  float* BiasATmB = ppe + (size_t)EKZ*BSZ*MC;
  float* eqpart16 = BiasATmB + (size_t)BSZ*MC;
  float* ineqpart = eqpart16 + (size_t)16*MC;
  int*   flags    = (int*)(ineqpart + (size_t)16*NV);
  _Float16* Wzh = (_Float16*)(flags + 4);
  _Float16* Wzl = Wzh + (size_t)NV*NV;
  _Float16* Wbt = Wzl + (size_t)NV*NV;
  _Float16* rzh = Wbt + (size_t)MC*NV;
  _Float16* rzl = rzh + (size_t)BSZ*NV;

  // prologue scratch aliases inside the (not-yet-written) Wz pair region:
  _Float16* PBh = Wzh;
  _Float16* PBl = Wzh + (size_t)8*1024*1024;
  _Float16* bph = Wzl;
  _Float16* bpl = bph + (size_t)BSZ*MC;
  float*    hbuf = (float*)(bpl + (size_t)BSZ*MC);
  _Float16* hph = (_Float16*)(hbuf + (size_t)BSZ*HID);
  _Float16* hpl = hph + (size_t)BSZ*HID;
  _Float16* Bsh = hpl + (size_t)BSZ*HID;
  _Float16* Bsl = Bsh + (size_t)BSZ*NV;
  _Float16* zh0 = rzh;   // packed z0 pair borrows rz buffers
  _Float16* zl0 = rzl;

  const dim3 blk(256);

  if (fp16path){
    hipLaunchKernelGGL(init_k, dim3(1), dim3(1), 0, stream, flags);

    // ---- MLP via pair-MFMA (linear operands) ----
    hipLaunchKernelGGL(split_k, dim3((BSZ*(size_t)MC)/1024), blk, 0, stream, bp, bph, bpl, (int)((BSZ*(size_t)MC)/4));
    hipLaunchKernelGGL(trsplit2_k, dim3(MC/64, HID/64), blk, 0, stream, w1, PBh, PBl, MC, HID);
    hipLaunchKernelGGL(pairgemm_k, dim3(HID/128, 2, 4), blk, 0, stream,
                       bph, bpl, PBh, PBl, pp, HID, MC, 4, flags);
    hipLaunchKernelGGL(sumn_k, dim3(HID/256, 16), blk, 0, stream,
                       pp, 4, HID, b1, nullptr, 1, 0, hbuf, (_Float16*)nullptr, (_Float16*)nullptr, flags);
    hipLaunchKernelGGL(ln_k, dim3(BSZ), blk, 0, stream, hbuf, g1, be1);
    hipLaunchKernelGGL(split_k, dim3((BSZ*(size_t)HID)/1024), blk, 0, stream, hbuf, hph, hpl, (int)((BSZ*(size_t)HID)/4));
    hipLaunchKernelGGL(trsplit2_k, dim3(HID/64, HID/64), blk, 0, stream, w2, PBh, PBl, HID, HID);
    hipLaunchKernelGGL(pairgemm_k, dim3(HID/128, 2, 4), blk, 0, stream,
                       hph, hpl, PBh, PBl, pp, HID, HID, 4, flags);
    hipLaunchKernelGGL(sumn_k, dim3(HID/256, 16), blk, 0, stream,
                       pp, 4, HID, b2, nullptr, 1, 0, hbuf, (_Float16*)nullptr, (_Float16*)nullptr, flags);
    hipLaunchKernelGGL(ln_k, dim3(BSZ), blk, 0, stream, hbuf, g2, be2);
    hipLaunchKernelGGL(split_k, dim3((BSZ*(size_t)HID)/1024), blk, 0, stream, hbuf, hph, hpl, (int)((BSZ*(size_t)HID)/4));
    hipLaunchKernelGGL(trsplit2_k, dim3(HID/64, HID/64), blk, 0, stream, w3, PBh, PBl, HID, HID);
    hipLaunchKernelGGL(pairgemm_k, dim3(HID/128, 2, 4), blk, 0, stream,
                       hph, hpl, PBh, PBl, pp, HID, HID, 4, flags);
    hipLaunchKernelGGL(sumn_k, dim3(HID/256, 16), blk, 0, stream,
                       pp, 4, HID, b3, nullptr, 1, 0, hbuf, (_Float16*)nullptr, (_Float16*)nullptr, flags);
    hipLaunchKernelGGL(ln_k, dim3(BSZ), blk, 0, stream, hbuf, g3, be3);
    hipLaunchKernelGGL(split_k, dim3((BSZ*(size_t)HID)/1024), blk, 0, stream, hbuf, hph, hpl, (int)((BSZ*(size_t)HID)/4));
    // z0 = h3 @ wo + bo  -> z0 f32 (d_out) + PACKED pair into zh0/zl0
    hipLaunchKernelGGL(trsplit2_k, dim3(HID/64, NV/64), blk, 0, stream, wo, PBh, PBl, HID, NV);
    hipLaunchKernelGGL(pairgemm_k, dim3(NV/128, 2, 4), blk, 0, stream,
                       hph, hpl, PBh, PBl, pp, NV, HID, 4, flags);
    hipLaunchKernelGGL(sumn_k, dim3(NV/256, 16), blk, 0, stream,
                       pp, 4, NV, bo, nullptr, 0, 1, z0, zh0, zl0, flags);
    // Bias = bp @ WbProj^T  (linear pair out for next pairgemm)
    hipLaunchKernelGGL(split_k, dim3((NV*(size_t)MC)/1024), blk, 0, stream, Wb, PBh, PBl, (int)((NV*(size_t)MC)/4));
    hipLaunchKernelGGL(pairgemm_k, dim3(NV/128, 2, 4), blk, 0, stream,
                       bph, bpl, PBh, PBl, pp, NV, MC, 4, flags);
    hipLaunchKernelGGL(sumn_k, dim3(NV/256, 16), blk, 0, stream,
                       pp, 4, NV, nullptr, nullptr, 0, 0, BiasM, Bsh, Bsl, flags);
    // BiasATmB = Bias @ A^T - bp
    hipLaunchKernelGGL(split_k, dim3((MC*(size_t)NV)/1024), blk, 0, stream, A, PBh, PBl, (int)((MC*(size_t)NV)/4));
    hipLaunchKernelGGL(pairgemm_k, dim3(MC/128, 2, 4), blk, 0, stream,
                       Bsh, Bsl, PBh, PBl, pp, MC, NV, 4, flags);
    hipLaunchKernelGGL(sumn_k, dim3(MC/256, 16), blk, 0, stream,
                       pp, 4, MC, nullptr, bp, 0, 0, BiasATmB, (_Float16*)nullptr, (_Float16*)nullptr, flags);
    // loop constants: PACKED Wbt + PACKED Wz pair (overwrites prologue aliases)
    hipLaunchKernelGGL(trsplit_k, dim3(NV/64, MC/64), blk, 0, stream, Wb, Wbt);
    hipLaunchKernelGGL(splitpack_k, dim3((NV*(size_t)NV/8 + 255)/256), blk, 0, stream, Wz, Wzh, Wzl, NV, NV);

    // bootstrap: z_init = Bias + z0 @ Wp (proj only)
    hipLaunchKernelGGL(fusedm_k, dim3(64*PKZ), blk, 0, stream,
                       zh0, zl0, Wzh, Wzl, Wbt, pp, ppe, PKZ, EKZ, flags);
    hipLaunchKernelGGL(combineN_k, dim3(NV/256, 16), blk, 0, stream,
                       pp, BiasM, zbuf, rzh, rzl, ineqpart, PKZ, flags);

    const int loopGrid = 64*PKZ + 32*EKZ;
    for (int j=1; j<=NITER; ++j){
      hipLaunchKernelGGL(fusedm_k, dim3(loopGrid), blk, 0, stream,
                         rzh, rzl, Wzh, Wzl, Wbt, pp, ppe, PKZ, EKZ, flags);
      hipLaunchKernelGGL(combineN_k, dim3(NV/256, 16), blk, 0, stream,
                         pp, BiasM, zbuf, rzh, rzl, ineqpart, PKZ, flags);
      hipLaunchKernelGGL(eqredN_k, dim3(MC/256, 16), blk, 0, stream,
                         ppe, BiasATmB, eqpart16, EKZ, flags);
      hipLaunchKernelGGL(check3_k, dim3((MC + (NV-FREEN))/256), blk, 0, stream,
                         eqpart16, ineqpart, flags+2, flags);
      hipLaunchKernelGGL(update_k, dim3(1), dim3(1), 0, stream, flags);
    }
    hipLaunchKernelGGL(finalp_k, dim3(1), dim3(1), 0, stream, out, flags);
  } else {
    // fallback: proven f32 loop
    float* ftmp1 = ws_f;
    float* ftmp2 = ftmp1 + (size_t)BSZ*HID;
    float* fBias = ftmp2 + (size_t)BSZ*HID;
    float* fbuf1 = fBias + (size_t)BSZ*NV;
    float* feqp  = fbuf1 + (size_t)BSZ*NV;
    int*   ffl   = (int*)(feqp + 8*MC);

    hipLaunchKernelGGL(init_k, dim3(1), dim3(1), 0, stream, ffl);
    hipLaunchKernelGGL((gemm_k<64,64,32,4,4,false,false,EPI_BIASRELU>), dim3(HID/64, BSZ/64), blk, 0, stream,
                       bp, MC, w1, HID, ftmp1, MC, HID, b1, nullptr, 0, nullptr);
    hipLaunchKernelGGL(ln_k, dim3(BSZ), blk, 0, stream, ftmp1, g1, be1);
    hipLaunchKernelGGL((gemm_k<64,64,32,4,4,false,false,EPI_BIASRELU>), dim3(HID/64, BSZ/64), blk, 0, stream,
                       ftmp1, HID, w2, HID, ftmp2, HID, HID, b2, nullptr, 0, nullptr);
    hipLaunchKernelGGL(ln_k, dim3(BSZ), blk, 0, stream, ftmp2, g2, be2);
    hipLaunchKernelGGL((gemm_k<64,64,32,4,4,false,false,EPI_BIASRELU>), dim3(HID/64, BSZ/64), blk, 0, stream,
                       ftmp2, HID, w3, HID, ftmp1, HID, HID, b3, nullptr, 0, nullptr);
    hipLaunchKernelGGL(ln_k, dim3(BSZ), blk, 0, stream, ftmp1, g3, be3);
    hipLaunchKernelGGL((gemm_k<64,64,32,4,4,false,false,EPI_BIAS>), dim3(NV/64, BSZ/64), blk, 0, stream,
                       ftmp1, HID, wo, NV, z0, HID, NV, bo, nullptr, 0, nullptr);
    hipLaunchKernelGGL((gemm_k<64,64,32,4,4,true,false,EPI_NONE>), dim3(NV/64, BSZ/64), blk, 0, stream,
                       bp, MC, Wb, MC, fBias, MC, NV, nullptr, nullptr, 0, nullptr);
    hipLaunchKernelGGL((gemm_k<64,64,32,4,4,true,false,EPI_ADDMAT>), dim3(NV/64, BSZ/64), blk, 0, stream,
                       z0, NV, Wz, NV, out, NV, NV, nullptr, fBias, NV, nullptr);
    for (int j=1; j<=NITER; ++j){
      float* src = (j&1) ? out : fbuf1;
      float* dst = (j&1) ? fbuf1 : out;
      hipLaunchKernelGGL((gemm_k<64,64,32,4,4,true,true,EPI_ADDMAT>), dim3(NV/64, BSZ/64), blk, 0, stream,
                         src, NV, Wz, NV, dst, NV, NV, nullptr, fBias, NV, ffl);
      hipLaunchKernelGGL((gemm_k<32,64,32,2,4,true,false,EPI_EQ>), dim3(MC/64, BSZ/32), blk, 0, stream,
                         dst, NV, A, NV, feqp, NV, MC, nullptr, bp, MC, ffl);
      hipLaunchKernelGGL(check_k, dim3((MC + (NV-FREEN))/256), blk, 0, stream, feqp, dst, ffl+2, ffl, 8);
      hipLaunchKernelGGL(update_k, dim3(1), dim3(1), 0, stream, ffl);
    }
    hipLaunchKernelGGL(final_k, dim3((BSZ*NV)/256), blk, 0, stream, fbuf1, out, ffl);
  }

  (void)in_sizes; (void)n_in; (void)out_size; (void)ws_size;
}

// Round 10
// 5101.104 us; speedup vs baseline: 1.0110x; 1.0110x over previous
//
#include <hip/hip_runtime.h>
#include <math.h>

#define BSZ 256
#define NV  4096
#define MC  2048
#define HID 1024
#define FREEN 512
#define NITER 31
#define TOLF 1e-4f
#define EPSF 1e-6f
#define INV2048 4.8828125e-4f

typedef _Float16 half8 __attribute__((ext_vector_type(8)));
typedef float f32x16 __attribute__((ext_vector_type(16)));

enum { EPI_NONE=0, EPI_BIASRELU=1, EPI_BIAS=2, EPI_ADDMAT=3, EPI_EQ=4, EPI_SUBMAT=5 };

// Packed operand layout: matrix [R rows][K k] as tiles of 128 rows x 32 k.
// tile index = (row>>7)*(K/32) + (k>>5); within tile: oct*1024 + (row&127)*8 + (k&7)
// A staged tile is then a LINEAR 8KB copy of one global tile.

// ---------------- f32 vector-ALU GEMM (fallback path only) ----------------
template<int BM,int BN,int BK,int TM,int TN,bool TB,bool RELUIN,int EPI>
__global__ __launch_bounds__(256)
void gemm_k(const float* __restrict__ X, int ldx,
            const float* __restrict__ W, int ldw,
            float* __restrict__ C,
            int K, int N,
            const float* __restrict__ bvec,
            const float* __restrict__ addm, int ldadd,
            const int* __restrict__ guard)
{
  if (guard && guard[0]) return;
  const int t = (int)threadIdx.x;
  const int m0 = (int)blockIdx.y*BM, n0 = (int)blockIdx.x*BN;
  __shared__ float As[BK][BM+4];
  __shared__ float Bs[BK][BN+4];
  constexpr int TX = BN/TN;
  const int tx = t % TX, ty = t / TX;
  constexpr int ALD = (BM*BK)/1024;
  constexpr int BLD = (BN*BK)/1024;
  float4 pa[ALD], pb[BLD];
  float acc[TM][TN];
  #pragma unroll
  for (int i=0;i<TM;i++)
    #pragma unroll
    for (int j=0;j<TN;j++) acc[i][j]=0.f;

  const int nk = K/BK;

  auto loadA = [&](int kt){
    const int k0 = kt*BK;
    const bool rl = RELUIN && (k0 >= FREEN);
    #pragma unroll
    for (int q=0;q<ALD;q++){
      const int idx = q*256 + t;
      const int r = idx/(BK/4), c4 = (idx%(BK/4))*4;
      float4 v = *reinterpret_cast<const float4*>(&X[(size_t)(m0+r)*ldx + k0 + c4]);
      if (rl){ v.x=fmaxf(v.x,0.f); v.y=fmaxf(v.y,0.f); v.z=fmaxf(v.z,0.f); v.w=fmaxf(v.w,0.f); }
      pa[q]=v;
    }
  };
  auto loadB = [&](int kt){
    const int k0 = kt*BK;
    #pragma unroll
    for (int q=0;q<BLD;q++){
      const int idx = q*256 + t;
      if (TB){
        const int r = idx/(BK/4), c4 = (idx%(BK/4))*4;
        pb[q] = *reinterpret_cast<const float4*>(&W[(size_t)(n0+r)*ldw + k0 + c4]);
      } else {
        const int r = idx/(BN/4), c4 = (idx%(BN/4))*4;
        pb[q] = *reinterpret_cast<const float4*>(&W[(size_t)(k0+r)*ldw + n0 + c4]);
      }
    }
  };
  auto stor = [&](){
    #pragma unroll
    for (int q=0;q<ALD;q++){
      const int idx = q*256 + t;
      const int r = idx/(BK/4), c4 = (idx%(BK/4))*4;
      As[c4+0][r]=pa[q].x; As[c4+1][r]=pa[q].y; As[c4+2][r]=pa[q].z; As[c4+3][r]=pa[q].w;
    }
    #pragma unroll
    for (int q=0;q<BLD;q++){
      const int idx = q*256 + t;
      if (TB){
        const int r = idx/(BK/4), c4 = (idx%(BK/4))*4;
        Bs[c4+0][r]=pb[q].x; Bs[c4+1][r]=pb[q].y; Bs[c4+2][r]=pb[q].z; Bs[c4+3][r]=pb[q].w;
      } else {
        const int r = idx/(BN/4), c4 = (idx%(BN/4))*4;
        *reinterpret_cast<float4*>(&Bs[r][c4]) = pb[q];
      }
    }
  };

  loadA(0); loadB(0);
  for (int kt=0; kt<nk; ++kt){
    __syncthreads();
    stor();
    __syncthreads();
    if (kt+1 < nk){ loadA(kt+1); loadB(kt+1); }
    #pragma unroll
    for (int kk=0; kk<BK; ++kk){
      float a[TM], b[TN];
      if constexpr (TM==4) *reinterpret_cast<float4*>(a) = *reinterpret_cast<const float4*>(&As[kk][ty*TM]);
      else                 *reinterpret_cast<float2*>(a) = *reinterpret_cast<const float2*>(&As[kk][ty*TM]);
      if constexpr (TN==4) *reinterpret_cast<float4*>(b) = *reinterpret_cast<const float4*>(&Bs[kk][tx*TN]);
      else                 *reinterpret_cast<float2*>(b) = *reinterpret_cast<const float2*>(&Bs[kk][tx*TN]);
      #pragma unroll
      for (int i=0;i<TM;i++)
        #pragma unroll
        for (int j=0;j<TN;j++)
          acc[i][j] = fmaf(a[i], b[j], acc[i][j]);
    }
  }

  if constexpr (EPI==EPI_EQ){
    float csum[TN];
    #pragma unroll
    for (int j=0;j<TN;j++) csum[j]=0.f;
    #pragma unroll
    for (int i=0;i<TM;i++){
      const int r = m0 + ty*TM + i;
      #pragma unroll
      for (int j=0;j<TN;j++){
        const int c = n0 + tx*TN + j;
        const float v = acc[i][j] - addm[(size_t)r*ldadd + c];
        csum[j] += fabsf(v);
      }
    }
    __syncthreads();
    float* red = &As[0][0];
    constexpr int RY = BM/TM;
    #pragma unroll
    for (int j=0;j<TN;j++) red[(tx*TN+j)*RY + ty] = csum[j];
    __syncthreads();
    if (t < BN){
      float s=0.f;
      #pragma unroll
      for (int y=0;y<RY;y++) s += red[t*RY + y];
      C[(size_t)blockIdx.y*N + n0 + t] = s;
    }
  } else {
    #pragma unroll
    for (int i=0;i<TM;i++){
      const int r = m0 + ty*TM + i;
      #pragma unroll
      for (int j=0;j<TN;j++){
        const int c = n0 + tx*TN + j;
        float v = acc[i][j];
        if constexpr (EPI==EPI_BIASRELU){ v += bvec[c]; v = fmaxf(v,0.f); }
        if constexpr (EPI==EPI_BIAS)    { v += bvec[c]; }
        if constexpr (EPI==EPI_ADDMAT)  { v += addm[(size_t)r*ldadd + c]; }
        if constexpr (EPI==EPI_SUBMAT)  { v -= addm[(size_t)r*ldadd + c]; }
        C[(size_t)r*N + c] = v;
      }
    }
  }
}

// ---------------- split helper ----------------
__device__ __forceinline__ void split_f32(float v, _Float16& h, _Float16& l){
  float hf = 0.f;
  _Float16 hh = (_Float16)0.f;
  if (fabsf(v) >= 6.103515625e-05f) { hh = (_Float16)v; hf = (float)hh; }
  h = hh;
  l = (_Float16)((v - hf) * 2048.0f);
}

// ---------------- LDS-tiled pack: f32 [R][K] -> packed pair (coalesced both sides) ----
template<bool RELU>
__global__ __launch_bounds__(256)
void packpair_k(const float* __restrict__ src, _Float16* __restrict__ oh,
                _Float16* __restrict__ ol, int R, int K,
                const int* __restrict__ guard)
{
  if (guard && guard[0]) return;
  __shared__ float ts[128][33];
  const int t = (int)threadIdx.x;
  const int bid = (int)blockIdx.x;
  const int KT = K >> 5;
  const int rt = bid / KT, kt = bid % KT;
  const bool rl = RELU && (kt*32 >= FREEN);
  #pragma unroll
  for (int p=0;p<4;p++){
    const int row = p*32 + (t>>3);
    const int c4 = (t&7)*4;
    float4 v = *reinterpret_cast<const float4*>(&src[(size_t)(rt*128+row)*K + kt*32 + c4]);
    ts[row][c4+0]=v.x; ts[row][c4+1]=v.y; ts[row][c4+2]=v.z; ts[row][c4+3]=v.w;
  }
  __syncthreads();
  const int oct = t >> 6;
  const size_t tb = (size_t)bid*4096;
  #pragma unroll
  for (int rr=0; rr<2; ++rr){
    const int row = (t&63)*2 + rr;
    half8 hh, ll;
    #pragma unroll
    for (int j=0;j<8;j++){
      float v = ts[row][oct*8+j];
      if (rl) v = fmaxf(v, 0.f);
      _Float16 h,l; split_f32(v,h,l); hh[j]=h; ll[j]=l;
    }
    const size_t o = tb + (size_t)oct*1024 + row*8;
    *reinterpret_cast<half8*>(&oh[o]) = hh;
    if (ol) *reinterpret_cast<half8*>(&ol[o]) = ll;
  }
}

// ---------------- LDS-tiled transpose-pack: src [R][C] f32 -> packed pair of src^T ([C][R]) ----
__global__ __launch_bounds__(256)
void trpackpair_k(const float* __restrict__ src, _Float16* __restrict__ oh,
                  _Float16* __restrict__ ol, int R, int C)
{
  __shared__ float ts[32][129];
  const int t = (int)threadIdx.x;
  const int bid = (int)blockIdx.x;
  const int KT = R >> 5;                    // out Kdim = R
  const int rt = bid / KT, kt = bid % KT;   // rt over C/128, kt over R/32
  const int r0 = kt*32, c0 = rt*128;
  #pragma unroll
  for (int p=0;p<4;p++){
    const int sr = p*8 + (t>>5);
    const int sc4 = (t&31)*4;
    float4 v = *reinterpret_cast<const float4*>(&src[(size_t)(r0+sr)*C + c0 + sc4]);
    ts[sr][sc4+0]=v.x; ts[sr][sc4+1]=v.y; ts[sr][sc4+2]=v.z; ts[sr][sc4+3]=v.w;
  }
  __syncthreads();
  const int oct = t >> 6;
  const size_t tb = (size_t)bid*4096;
  #pragma unroll
  for (int rr=0; rr<2; ++rr){
    const int row = (t&63)*2 + rr;          // out row = src col
    half8 hh, ll;
    #pragma unroll
    for (int j=0;j<8;j++){
      _Float16 h,l; split_f32(ts[oct*8+j][row], h, l); hh[j]=h; ll[j]=l;
    }
    const size_t o = tb + (size_t)oct*1024 + row*8;
    *reinterpret_cast<half8*>(&oh[o]) = hh;
    if (ol) *reinterpret_cast<half8*>(&ol[o]) = ll;
  }
}

// ---------------- fp16x2 pair-GEMM (prologue, packed operands) ----------------
__global__ __launch_bounds__(256)
void pairgemm_k(const _Float16* __restrict__ Ahg, const _Float16* __restrict__ Alg,
                const _Float16* __restrict__ Bhg, const _Float16* __restrict__ Blg,
                float* __restrict__ partial, int N, int K, int kzn,
                const int* __restrict__ guard)
{
  if (guard[0]) return;
  __shared__ _Float16 lds[2][8192];
  const int t = (int)threadIdx.x;
  const int lane = t & 63, wid = t >> 6;
  const int wr = wid >> 1, wc = wid & 1;
  const int ln = lane & 31, lg = lane >> 5;

  const int nt = (int)blockIdx.x, mt = (int)blockIdx.y, kz = (int)blockIdx.z;
  const int m0 = mt*128, n0 = nt*128;
  const int chunk = (3*K)/kzn;
  const int loExt = kz*chunk;
  const int nsteps = chunk/32;
  int ss = (2*K - loExt)/32;
  const int scaleStep = ss < 0 ? 0 : ss;
  const int KT = K >> 5;

  f32x16 acc[2][2];
  #pragma unroll
  for (int fm=0;fm<2;fm++)
    #pragma unroll
    for (int fn=0;fn<2;fn++)
      #pragma unroll
      for (int r=0;r<16;r++) acc[fm][fn][r] = 0.f;

  auto stage = [&](int i, int buf){
    const int gext = loExt + i*32;
    const _Float16* aB; const _Float16* bB; int kk;
    if (gext < K)         { aB = Ahg; bB = Blg; kk = gext; }
    else if (gext < 2*K)  { aB = Alg; bB = Bhg; kk = gext - K; }
    else                  { aB = Ahg; bB = Bhg; kk = gext - 2*K; }
    const int kt = kk >> 5;
    const _Float16* aT = aB + ((size_t)(mt*KT + kt))*4096;
    const _Float16* bT = bB + ((size_t)((n0>>7)*KT + kt))*4096;
    _Float16* base = &lds[buf][0];
    #pragma unroll
    for (int q=0;q<2;q++){
      const int W = q*4 + wid;
      __builtin_amdgcn_global_load_lds(
        (const __attribute__((address_space(1))) void*)(aT + W*512 + lane*8),
        (__attribute__((address_space(3))) void*)(base + W*512), 16, 0, 0);
      __builtin_amdgcn_global_load_lds(
        (const __attribute__((address_space(1))) void*)(bT + W*512 + lane*8),
        (__attribute__((address_space(3))) void*)(base + 4096 + W*512), 16, 0, 0);
    }
  };

  int cur = 0;
  stage(0, 0);
  __syncthreads();
  for (int i=0; i<nsteps; ++i){
    if (i+1 < nsteps) stage(i+1, cur^1);
    const _Float16* As = &lds[cur][0];
    const _Float16* Bs = &lds[cur][4096];
    half8 a[2][2], b[2][2];
    #pragma unroll
    for (int fm=0; fm<2; ++fm){
      const int row = wr*64 + fm*32 + ln;
      #pragma unroll
      for (int ks=0; ks<2; ++ks)
        a[fm][ks] = *reinterpret_cast<const half8*>(&As[(ks*2+lg)*1024 + row*8]);
    }
    #pragma unroll
    for (int fn=0; fn<2; ++fn){
      const int row = wc*64 + fn*32 + ln;
      #pragma unroll
      for (int ks=0; ks<2; ++ks)
        b[fn][ks] = *reinterpret_cast<const half8*>(&Bs[(ks*2+lg)*1024 + row*8]);
    }
    if (i == scaleStep){
      #pragma unroll
      for (int fm=0;fm<2;fm++)
        #pragma unroll
        for (int fn=0;fn<2;fn++)
          #pragma unroll
          for (int r=0;r<16;r++) acc[fm][fn][r] *= INV2048;
    }
    #pragma unroll
    for (int ks=0; ks<2; ++ks)
      #pragma unroll
      for (int fm=0; fm<2; ++fm)
        #pragma unroll
        for (int fn=0; fn<2; ++fn)
          acc[fm][fn] = __builtin_amdgcn_mfma_f32_32x32x16_f16(a[fm][ks], b[fn][ks], acc[fm][fn], 0, 0, 0);
    __syncthreads();
    cur ^= 1;
  }
  if (scaleStep >= nsteps){
    #pragma unroll
    for (int fm=0;fm<2;fm++)
      #pragma unroll
      for (int fn=0;fn<2;fn++)
        #pragma unroll
        for (int r=0;r<16;r++) acc[fm][fn][r] *= INV2048;
  }

  float* __restrict__ dst = partial + (size_t)kz*BSZ*N;
  #pragma unroll
  for (int fm=0; fm<2; ++fm)
    #pragma unroll
    for (int fn=0; fn<2; ++fn)
      #pragma unroll
      for (int r=0; r<16; ++r){
        const int row = (r&3) + 8*(r>>2) + 4*lg;
        const int gm = m0 + wr*64 + fm*32 + row;
        const int gn = n0 + wc*64 + fn*32 + ln;
        dst[(size_t)gm*N + gn] = acc[fm][fn][r];
      }
}

// sum of kz partials + f32 epilogue. grid (N/256, 16)
__global__ __launch_bounds__(256)
void sumn_k(const float* __restrict__ partial, int ng, int N,
            const float* __restrict__ bvec, const float* __restrict__ subm,
            int relu, float* __restrict__ outf, const int* __restrict__ guard)
{
  if (guard && guard[0]) return;
  const int c = blockIdx.x*256 + threadIdx.x;
  const int rb = blockIdx.y;
  const size_t SZ = (size_t)BSZ*N;
  for (int r=0; r<16; ++r){
    const size_t idx = (size_t)(rb*16+r)*N + c;
    float s = 0.f;
    for (int g=0; g<ng; ++g) s += partial[(size_t)g*SZ + idx];
    if (bvec) s += bvec[c];
    if (subm) s -= subm[idx];
    if (relu) s = fmaxf(s, 0.f);
    outf[idx] = s;
  }
}

// ---------------- fused loop MFMA kernel (packed, 2-segment dual-acc) ----------------
// ext-K = [Wzl-seg 4096 | Wzh-seg 4096]. seg0: ah*Wzl -> acc_c. seg1: al*Wzh -> acc_c,
// ah*Wzh -> acc_m (Wzh staged ONCE). out = acc_m + acc_c/2048. Chunk edges align with 4096.
// eq blocks (first eqCnt logical ids): ah * Wbt -> acc_m -> ppe[kz].
__global__ __launch_bounds__(256)
void fusedm_k(const _Float16* __restrict__ Ahg, const _Float16* __restrict__ Alg,
              const _Float16* __restrict__ Wzh, const _Float16* __restrict__ Wzl,
              const _Float16* __restrict__ Wbt,
              float* __restrict__ pp, float* __restrict__ ppe,
              int projKz, int eqKz, int eqCnt, const int* __restrict__ guard)
{
  if (guard[0]) return;
  __shared__ _Float16 lds[2][12288];   // [Ah 4096 | Al 4096 | B 4096] halfs
  const int t = (int)threadIdx.x;
  const int lane = t & 63, wid = t >> 6;
  const int wr = wid >> 1, wc = wid & 1;
  const int ln = lane & 31, lg = lane >> 5;

  const int nwg = (int)gridDim.x;
  const int hw = (int)blockIdx.x;
  const int L = (hw & 7)*(nwg >> 3) + (hw >> 3);

  const bool is_eq = L < eqCnt;
  int kz, mt, nt, nsteps, kbase = 0, loExt = 0;
  bool dual = false;
  if (is_eq){
    mt = L & 1;
    kz = (L >> 1) % eqKz;
    nt = L / (2*eqKz);
    nsteps = (NV/eqKz) / 32;
    kbase = kz*(NV/eqKz);
  } else {
    const int P = L - eqCnt;
    mt = P & 1;
    kz = (P >> 1) % projKz;
    nt = P / (2*projKz);
    const int chunk = 8192 / projKz;
    loExt = kz * chunk;
    nsteps = chunk / 32;
    dual = (loExt >= 4096);
  }
  const int m0 = mt*128, n0 = nt*128;
  const int KT = NV >> 5;

  f32x16 accm[2][2], accc[2][2];
  #pragma unroll
  for (int fm=0;fm<2;fm++)
    #pragma unroll
    for (int fn=0;fn<2;fn++)
      #pragma unroll
      for (int r=0;r<16;r++){ accm[fm][fn][r]=0.f; accc[fm][fn][r]=0.f; }

  auto stage = [&](int i, int buf){
    const _Float16 *aTh, *bT;
    const _Float16 *aTl = nullptr;
    if (is_eq){
      const int kt = (kbase + i*32) >> 5;
      aTh = Ahg + ((size_t)(mt*KT + kt))*4096;
      bT  = Wbt + ((size_t)((n0>>7)*KT + kt))*4096;
    } else {
      const int gext = loExt + i*32;
      const int kt = (dual ? (gext - 4096) : gext) >> 5;
      aTh = Ahg + ((size_t)(mt*KT + kt))*4096;
      if (dual) aTl = Alg + ((size_t)(mt*KT + kt))*4096;
      bT = (dual ? Wzh : Wzl) + ((size_t)((n0>>7)*KT + kt))*4096;
    }
    _Float16* base = &lds[buf][0];
    #pragma unroll
    for (int q=0;q<2;q++){
      const int W = q*4 + wid;
      __builtin_amdgcn_global_load_lds(
        (const __attribute__((address_space(1))) void*)(aTh + W*512 + lane*8),
        (__attribute__((address_space(3))) void*)(base + W*512), 16, 0, 0);
      if (aTl)
        __builtin_amdgcn_global_load_lds(
          (const __attribute__((address_space(1))) void*)(aTl + W*512 + lane*8),
          (__attribute__((address_space(3))) void*)(base + 4096 + W*512), 16, 0, 0);
      __builtin_amdgcn_global_load_lds(
        (const __attribute__((address_space(1))) void*)(bT + W*512 + lane*8),
        (__attribute__((address_space(3))) void*)(base + 8192 + W*512), 16, 0, 0);
    }
  };

  int cur = 0;
  stage(0, 0);
  __syncthreads();
  for (int i=0; i<nsteps; ++i){
    if (i+1 < nsteps) stage(i+1, cur^1);
    const _Float16* As = &lds[cur][0];
    const _Float16* Al = &lds[cur][4096];
    const _Float16* Bs = &lds[cur][8192];
    half8 ah[2][2], al[2][2], b[2][2];
    #pragma unroll
    for (int fm=0; fm<2; ++fm){
      const int row = wr*64 + fm*32 + ln;
      #pragma unroll
      for (int ks=0; ks<2; ++ks){
        ah[fm][ks] = *reinterpret_cast<const half8*>(&As[(ks*2+lg)*1024 + row*8]);
        if (dual) al[fm][ks] = *reinterpret_cast<const half8*>(&Al[(ks*2+lg)*1024 + row*8]);
      }
    }
    #pragma unroll
    for (int fn=0; fn<2; ++fn){
      const int row = wc*64 + fn*32 + ln;
      #pragma unroll
      for (int ks=0; ks<2; ++ks)
        b[fn][ks] = *reinterpret_cast<const half8*>(&Bs[(ks*2+lg)*1024 + row*8]);
    }
    #pragma unroll
    for (int ks=0; ks<2; ++ks)
      #pragma unroll
      for (int fm=0; fm<2; ++fm)
        #pragma unroll
        for (int fn=0; fn<2; ++fn){
          if (is_eq){
            accm[fm][fn] = __builtin_amdgcn_mfma_f32_32x32x16_f16(ah[fm][ks], b[fn][ks], accm[fm][fn], 0, 0, 0);
          } else if (dual){
            accc[fm][fn] = __builtin_amdgcn_mfma_f32_32x32x16_f16(al[fm][ks], b[fn][ks], accc[fm][fn], 0, 0, 0);
            accm[fm][fn] = __builtin_amdgcn_mfma_f32_32x32x16_f16(ah[fm][ks], b[fn][ks], accm[fm][fn], 0, 0, 0);
          } else {
            accc[fm][fn] = __builtin_amdgcn_mfma_f32_32x32x16_f16(ah[fm][ks], b[fn][ks], accc[fm][fn], 0, 0, 0);
          }
        }
    __syncthreads();
    cur ^= 1;
  }

  if (is_eq){
    float* __restrict__ dst = ppe + (size_t)kz*BSZ*MC;
    #pragma unroll
    for (int fm=0; fm<2; ++fm)
      #pragma unroll
      for (int fn=0; fn<2; ++fn)
        #pragma unroll
        for (int r=0; r<16; ++r){
          const int row = (r&3) + 8*(r>>2) + 4*lg;
          const int gm = m0 + wr*64 + fm*32 + row;
          const int gn = n0 + wc*64 + fn*32 + ln;
          dst[(size_t)gm*MC + gn] = accm[fm][fn][r];
        }
  } else {
    float* __restrict__ dst = pp + (size_t)kz*BSZ*NV;
    #pragma unroll
    for (int fm=0; fm<2; ++fm)
      #pragma unroll
      for (int fn=0; fn<2; ++fn)
        #pragma unroll
        for (int r=0; r<16; ++r){
          const int row = (r&3) + 8*(r>>2) + 4*lg;
          const int gm = m0 + wr*64 + fm*32 + row;
          const int gn = n0 + wc*64 + fn*32 + ln;
          dst[(size_t)gm*NV + gn] = accm[fm][fn][r] + accc[fm][fn][r]*INV2048;
        }
  }
}

// combine + ineq + relu-split-pack, fully tiled/coalesced. grid = (BSZ/128)*(NV/32) tiles.
__global__ __launch_bounds__(256)
void combinep_k(const float* __restrict__ pp, int ng, const float* __restrict__ BiasM,
                float* __restrict__ zout, _Float16* __restrict__ rzh,
                _Float16* __restrict__ rzl, float* __restrict__ ineqpart,
                const int* __restrict__ guard)
{
  if (guard[0]) return;
  __shared__ float ts[128][33];
  const int t = (int)threadIdx.x;
  const int bid = (int)blockIdx.x;
  const int rt = bid >> 7, kt = bid & 127;     // rt over 256/128, kt over 4096/32
  const size_t SZ = (size_t)BSZ*NV;
  // load + sum partials + Bias -> z tile in LDS, write zout
  #pragma unroll
  for (int p=0;p<4;p++){
    const int row = p*32 + (t>>3);
    const int c4 = (t&7)*4;
    const size_t idx = (size_t)(rt*128+row)*NV + kt*32 + c4;
    float4 z = *reinterpret_cast<const float4*>(&BiasM[idx]);
    for (int g=0; g<ng; ++g){
      const float4 v = *reinterpret_cast<const float4*>(&pp[(size_t)g*SZ + idx]);
      z.x+=v.x; z.y+=v.y; z.z+=v.z; z.w+=v.w;
    }
    *reinterpret_cast<float4*>(&zout[idx]) = z;
    ts[row][c4+0]=z.x; ts[row][c4+1]=z.y; ts[row][c4+2]=z.z; ts[row][c4+3]=z.w;
  }
  __syncthreads();
  // ineq partials: thread (g 0-7, c 0-31): sum relu(-z) over 16 rows
  {
    const int g = t >> 5, c = t & 31;
    float s = 0.f;
    #pragma unroll
    for (int r=0;r<16;r++) s += fmaxf(-ts[g*16+r][c], 0.f);
    ineqpart[(size_t)(rt*8+g)*NV + kt*32 + c] = s;
  }
  // relu-split-pack -> rz pair (packed tile index == bid)
  const bool rl = (kt*32 >= FREEN);
  const int oct = t >> 6;
  const size_t tb = (size_t)bid*4096;
  #pragma unroll
  for (int rr=0; rr<2; ++rr){
    const int row = (t&63)*2 + rr;
    half8 hh, ll;
    #pragma unroll
    for (int j=0;j<8;j++){
      float v = ts[row][oct*8+j];
      if (rl) v = fmaxf(v, 0.f);
      _Float16 h,l; split_f32(v,h,l); hh[j]=h; ll[j]=l;
    }
    const size_t o = tb + (size_t)oct*1024 + row*8;
    *reinterpret_cast<half8*>(&rzh[o]) = hh;
    *reinterpret_cast<half8*>(&rzl[o]) = ll;
  }
}

__global__ __launch_bounds__(256)
void eqredN_k(const float* __restrict__ ppe, const float* __restrict__ BiasATmB,
              float* __restrict__ eqpart16, int ng, const int* __restrict__ guard)
{
  if (guard[0]) return;
  const int c = blockIdx.x*256 + threadIdx.x;
  const int rb = blockIdx.y;
  const size_t SE = (size_t)BSZ*MC;
  float s = 0.f;
  for (int r=0; r<16; ++r){
    const size_t idx = (size_t)(rb*16+r)*MC + c;
    float acc = 0.f;
    for (int g=0; g<ng; ++g) acc += ppe[(size_t)g*SE + idx];
    s += fabsf(BiasATmB[idx] + EPSF*acc);
  }
  eqpart16[(size_t)rb*MC + c] = s;
}

__global__ __launch_bounds__(256)
void check3_k(const float* __restrict__ eqpart16, const float* __restrict__ ineqpart,
              int* __restrict__ viol, const int* __restrict__ done)
{
  if (done[0]) return;
  const int id = blockIdx.x*256 + threadIdx.x;
  bool bad;
  if (id < MC){
    float s = 0.f;
    #pragma unroll
    for (int g=0; g<16; g++) s += eqpart16[(size_t)g*MC + id];
    bad = (s*(1.f/(float)BSZ) > TOLF);
  } else {
    const int c = FREEN + (id - MC);
    float s = 0.f;
    #pragma unroll
    for (int g=0; g<16; g++) s += ineqpart[(size_t)g*NV + c];
    bad = (s*(1.f/(float)BSZ) > TOLF);
  }
  if (bad) atomicAdd(viol, 1);
}

// ---------------- LayerNorm ----------------
__global__ __launch_bounds__(256)
void ln_k(float* __restrict__ x, const float* __restrict__ g, const float* __restrict__ b)
{
  const int row = blockIdx.x, t = threadIdx.x;
  float4 v = *reinterpret_cast<const float4*>(&x[(size_t)row*HID + t*4]);
  __shared__ float sm[256];
  sm[t] = v.x+v.y+v.z+v.w;
  __syncthreads();
  for (int st=128; st>0; st>>=1){ if (t<st) sm[t]+=sm[t+st]; __syncthreads(); }
  const float mu = sm[0]*(1.f/(float)HID);
  __syncthreads();
  const float dx=v.x-mu, dy=v.y-mu, dz=v.z-mu, dw=v.w-mu;
  sm[t] = dx*dx+dy*dy+dz*dz+dw*dw;
  __syncthreads();
  for (int st=128; st>0; st>>=1){ if (t<st) sm[t]+=sm[t+st]; __syncthreads(); }
  const float inv = 1.f/sqrtf(sm[0]*(1.f/(float)HID) + 1e-5f);
  const int c = t*4;
  const float4 gv = *reinterpret_cast<const float4*>(&g[c]);
  const float4 bv = *reinterpret_cast<const float4*>(&b[c]);
  float4 o;
  o.x = dx*inv*gv.x + bv.x; o.y = dy*inv*gv.y + bv.y;
  o.z = dz*inv*gv.z + bv.z; o.w = dw*inv*gv.w + bv.w;
  *reinterpret_cast<float4*>(&x[(size_t)row*HID + c]) = o;
}

// ---------------- flags / fallback machinery ----------------
__global__ __launch_bounds__(256)
void check_k(const float* __restrict__ eqpart, const float* __restrict__ znew,
             int* __restrict__ viol, const int* __restrict__ done, int ngroups)
{
  if (done[0]) return;
  const int id = blockIdx.x*256 + threadIdx.x;
  bool bad;
  if (id < MC){
    float s = 0.f;
    for (int g=0; g<ngroups; g++) s += eqpart[g*MC + id];
    bad = (s*(1.f/(float)BSZ) > TOLF);
  } else {
    const int c = FREEN + (id - MC);
    float s = 0.f;
    for (int r=0; r<BSZ; r++){
      const float v = znew[(size_t)r*NV + c];
      s += (v < 0.f) ? -v : 0.f;
    }
    bad = (s*(1.f/(float)BSZ) > TOLF);
  }
  if (bad) atomicAdd(viol, 1);
}

__global__ void init_k(int* flags){ flags[0]=0; flags[1]=0; flags[2]=0; }

__global__ void update_k(int* flags){
  if (!flags[0]){ flags[1] += 1; if (flags[2]==0) flags[0]=1; }
  flags[2] = 0;
}

__global__ __launch_bounds__(256)
void final_k(const float* __restrict__ buf1, float* __restrict__ out, const int* __restrict__ flags)
{
  const int i = blockIdx.x*256 + threadIdx.x;
  const int k = flags[1];
  if ((k & 1) && i < BSZ*NV) out[i] = buf1[i];
  if (i == 0) out[2*BSZ*NV] = (float)k;
}

__global__ void finalp_k(float* __restrict__ out, const int* __restrict__ flags)
{
  out[2*(size_t)BSZ*NV] = (float)flags[1];
}

// ---------------- host launch ----------------
extern "C" void kernel_launch(void* const* d_in, const int* in_sizes, int n_in,
                              void* d_out, int out_size, void* d_ws, size_t ws_size,
                              hipStream_t stream)
{
  const float* bp  = (const float*)d_in[0];
  const float* w1  = (const float*)d_in[1];
  const float* b1  = (const float*)d_in[2];
  const float* g1  = (const float*)d_in[3];
  const float* be1 = (const float*)d_in[4];
  const float* w2  = (const float*)d_in[5];
  const float* b2  = (const float*)d_in[6];
  const float* g2  = (const float*)d_in[7];
  const float* be2 = (const float*)d_in[8];
  const float* w3  = (const float*)d_in[9];
  const float* b3  = (const float*)d_in[10];
  const float* g3  = (const float*)d_in[11];
  const float* be3 = (const float*)d_in[12];
  const float* wo  = (const float*)d_in[13];
  const float* bo  = (const float*)d_in[14];
  const float* A   = (const float*)d_in[15];
  const float* Wz  = (const float*)d_in[16];
  const float* Wb  = (const float*)d_in[17];

  float* out  = (float*)d_out;
  float* z0   = out + (size_t)BSZ*NV;
  float* zbuf = out;

  auto layout_need = [&](int PKZ_, int EKZ_)->size_t{
    size_t f = (size_t)1048576*(1+PKZ_) + (size_t)524288*EKZ_ + 524288 + 32768 + 65536 + 16;
    size_t h = (size_t)NV*NV*2 + (size_t)MC*NV + (size_t)2*BSZ*NV;
    return f*4 + h*2;
  };
  int PKZ = 8, EKZ = 4;
  if (ws_size < layout_need(8,4)) { PKZ = 4; EKZ = 2; }
  const bool fp16path = (ws_size >= layout_need(PKZ, EKZ));
  const int KZBIG = (PKZ == 8) ? 6 : 4;   // kz for N-large prologue GEMMs (pp budget)

  float* ws_f = (float*)d_ws;
  float* BiasM    = ws_f;
  float* pp       = BiasM + (size_t)BSZ*NV;
  float* ppe      = pp + (size_t)PKZ*BSZ*NV;
  float* BiasATmB = ppe + (size_t)EKZ*BSZ*MC;
  float* eqpart16 = BiasATmB + (size_t)BSZ*MC;
  float* ineqpart = eqpart16 + (size_t)16*MC;
  int*   flags    = (int*)(ineqpart + (size_t)16*NV);
  _Float16* Wzh = (_Float16*)(flags + 16);
  _Float16* Wzl = Wzh + (size_t)NV*NV;
  _Float16* Wbt = Wzl + (size_t)NV*NV;
  _Float16* rzh = Wbt + (size_t)MC*NV;
  _Float16* rzl = rzh + (size_t)BSZ*NV;

  // prologue scratch aliases inside the (not-yet-written) Wz pair region:
  _Float16* PBh = Wzh;                                  // packed B hi (<=16MB)
  _Float16* PBl = Wzh + (size_t)NV*NV/2;                // packed B lo
  _Float16* bph = Wzl;                                  // bp pair (packed K=MC)
  _Float16* bpl = bph + (size_t)BSZ*MC;
  float*    hbuf = (float*)(bpl + (size_t)BSZ*MC);      // h f32
  _Float16* hph = (_Float16*)(hbuf + (size_t)BSZ*HID);  // h pair (packed K=HID)
  _Float16* hpl = hph + (size_t)BSZ*HID;
  _Float16* Bsh = hpl + (size_t)BSZ*HID;                // Bias pair (packed K=NV)
  _Float16* Bsl = Bsh + (size_t)BSZ*NV;
  _Float16* zh0 = rzh;                                  // packed z0 pair (borrow rz)
  _Float16* zl0 = rzl;

  const dim3 blk(256);

  if (fp16path){
    hipLaunchKernelGGL(init_k, dim3(1), dim3(1), 0, stream, flags);

    // ---- MLP via pair-MFMA (packed operands everywhere) ----
    hipLaunchKernelGGL((packpair_k<false>), dim3((BSZ/128)*(MC/32)), blk, 0, stream, bp, bph, bpl, BSZ, MC, nullptr);
    hipLaunchKernelGGL(trpackpair_k, dim3((HID/128)*(MC/32)), blk, 0, stream, w1, PBh, PBl, MC, HID);
    hipLaunchKernelGGL(pairgemm_k, dim3(HID/128, 2, 8), blk, 0, stream, bph, bpl, PBh, PBl, pp, HID, MC, 8, flags);
    hipLaunchKernelGGL(sumn_k, dim3(HID/256, 16), blk, 0, stream, pp, 8, HID, b1, nullptr, 1, hbuf, flags);
    hipLaunchKernelGGL(ln_k, dim3(BSZ), blk, 0, stream, hbuf, g1, be1);
    hipLaunchKernelGGL((packpair_k<false>), dim3((BSZ/128)*(HID/32)), blk, 0, stream, hbuf, hph, hpl, BSZ, HID, nullptr);

    hipLaunchKernelGGL(trpackpair_k, dim3((HID/128)*(HID/32)), blk, 0, stream, w2, PBh, PBl, HID, HID);
    hipLaunchKernelGGL(pairgemm_k, dim3(HID/128, 2, 8), blk, 0, stream, hph, hpl, PBh, PBl, pp, HID, HID, 8, flags);
    hipLaunchKernelGGL(sumn_k, dim3(HID/256, 16), blk, 0, stream, pp, 8, HID, b2, nullptr, 1, hbuf, flags);
    hipLaunchKernelGGL(ln_k, dim3(BSZ), blk, 0, stream, hbuf, g2, be2);
    hipLaunchKernelGGL((packpair_k<false>), dim3((BSZ/128)*(HID/32)), blk, 0, stream, hbuf, hph, hpl, BSZ, HID, nullptr);

    hipLaunchKernelGGL(trpackpair_k, dim3((HID/128)*(HID/32)), blk, 0, stream, w3, PBh, PBl, HID, HID);
    hipLaunchKernelGGL(pairgemm_k, dim3(HID/128, 2, 8), blk, 0, stream, hph, hpl, PBh, PBl, pp, HID, HID, 8, flags);
    hipLaunchKernelGGL(sumn_k, dim3(HID/256, 16), blk, 0, stream, pp, 8, HID, b3, nullptr, 1, hbuf, flags);
    hipLaunchKernelGGL(ln_k, dim3(BSZ), blk, 0, stream, hbuf, g3, be3);
    hipLaunchKernelGGL((packpair_k<false>), dim3((BSZ/128)*(HID/32)), blk, 0, stream, hbuf, hph, hpl, BSZ, HID, nullptr);

    // z0 = h3 @ wo + bo
    hipLaunchKernelGGL(trpackpair_k, dim3((NV/128)*(HID/32)), blk, 0, stream, wo, PBh, PBl, HID, NV);
    hipLaunchKernelGGL(pairgemm_k, dim3(NV/128, 2, KZBIG), blk, 0, stream, hph, hpl, PBh, PBl, pp, NV, HID, KZBIG, flags);
    hipLaunchKernelGGL(sumn_k, dim3(NV/256, 16), blk, 0, stream, pp, KZBIG, NV, bo, nullptr, 0, z0, flags);
    hipLaunchKernelGGL((packpair_k<false>), dim3((BSZ/128)*(NV/32)), blk, 0, stream, z0, zh0, zl0, BSZ, NV, nullptr);

    // Bias = bp @ WbProj^T  (B = Wb [NV][MC] native k-contig -> straight pack)
    hipLaunchKernelGGL((packpair_k<false>), dim3((NV/128)*(MC/32)), blk, 0, stream, Wb, PBh, PBl, NV, MC, nullptr);
    hipLaunchKernelGGL(pairgemm_k, dim3(NV/128, 2, KZBIG), blk, 0, stream, bph, bpl, PBh, PBl, pp, NV, MC, KZBIG, flags);
    hipLaunchKernelGGL(sumn_k, dim3(NV/256, 16), blk, 0, stream, pp, KZBIG, NV, nullptr, nullptr, 0, BiasM, flags);
    hipLaunchKernelGGL((packpair_k<false>), dim3((BSZ/128)*(NV/32)), blk, 0, stream, BiasM, Bsh, Bsl, BSZ, NV, nullptr);

    // BiasATmB = Bias @ A^T - bp  (B = A [MC][NV] native -> straight pack)
    hipLaunchKernelGGL((packpair_k<false>), dim3((MC/128)*(NV/32)), blk, 0, stream, A, PBh, PBl, MC, NV, nullptr);
    hipLaunchKernelGGL(pairgemm_k, dim3(MC/128, 2, KZBIG), blk, 0, stream, Bsh, Bsl, PBh, PBl, pp, MC, NV, KZBIG, flags);
    hipLaunchKernelGGL(sumn_k, dim3(MC/256, 16), blk, 0, stream, pp, KZBIG, MC, nullptr, bp, 0, BiasATmB, flags);

    // loop constants: packed Wbt (hi-only) + packed Wz pair (LAST: overwrites aliases)
    hipLaunchKernelGGL(trpackpair_k, dim3((MC/128)*(NV/32)), blk, 0, stream, Wb, Wbt, (_Float16*)nullptr, NV, MC);
    hipLaunchKernelGGL((packpair_k<false>), dim3((NV/128)*(NV/32)), blk, 0, stream, Wz, Wzh, Wzl, NV, NV, nullptr);

    // bootstrap: z_init = Bias + z0 @ Wp (proj blocks only)
    hipLaunchKernelGGL(fusedm_k, dim3(64*PKZ), blk, 0, stream,
                       zh0, zl0, Wzh, Wzl, Wbt, pp, ppe, PKZ, 1, 0, flags);
    hipLaunchKernelGGL(combinep_k, dim3((BSZ/128)*(NV/32)), blk, 0, stream,
                       pp, PKZ, BiasM, zbuf, rzh, rzl, ineqpart, flags);

    const int loopGrid = 32*EKZ + 64*PKZ;
    for (int j=1; j<=NITER; ++j){
      hipLaunchKernelGGL(fusedm_k, dim3(loopGrid), blk, 0, stream,
                         rzh, rzl, Wzh, Wzl, Wbt, pp, ppe, PKZ, EKZ, 32*EKZ, flags);
      hipLaunchKernelGGL(combinep_k, dim3((BSZ/128)*(NV/32)), blk, 0, stream,
                         pp, PKZ, BiasM, zbuf, rzh, rzl, ineqpart, flags);
      hipLaunchKernelGGL(eqredN_k, dim3(MC/256, 16), blk, 0, stream,
                         ppe, BiasATmB, eqpart16, EKZ, flags);
      hipLaunchKernelGGL(check3_k, dim3((MC + (NV-FREEN))/256), blk, 0, stream,
                         eqpart16, ineqpart, flags+2, flags);
      hipLaunchKernelGGL(update_k, dim3(1), dim3(1), 0, stream, flags);
    }
    hipLaunchKernelGGL(finalp_k, dim3(1), dim3(1), 0, stream, out, flags);
  } else {
    // fallback: proven f32 loop
    float* ftmp1 = ws_f;
    float* ftmp2 = ftmp1 + (size_t)BSZ*HID;
    float* fBias = ftmp2 + (size_t)BSZ*HID;
    float* fbuf1 = fBias + (size_t)BSZ*NV;
    float* feqp  = fbuf1 + (size_t)BSZ*NV;
    int*   ffl   = (int*)(feqp + 8*MC);

    hipLaunchKernelGGL(init_k, dim3(1), dim3(1), 0, stream, ffl);
    hipLaunchKernelGGL((gemm_k<64,64,32,4,4,false,false,EPI_BIASRELU>), dim3(HID/64, BSZ/64), blk, 0, stream,
                       bp, MC, w1, HID, ftmp1, MC, HID, b1, nullptr, 0, nullptr);
    hipLaunchKernelGGL(ln_k, dim3(BSZ), blk, 0, stream, ftmp1, g1, be1);
    hipLaunchKernelGGL((gemm_k<64,64,32,4,4,false,false,EPI_BIASRELU>), dim3(HID/64, BSZ/64), blk, 0, stream,
                       ftmp1, HID, w2, HID, ftmp2, HID, HID, b2, nullptr, 0, nullptr);
    hipLaunchKernelGGL(ln_k, dim3(BSZ), blk, 0, stream, ftmp2, g2, be2);
    hipLaunchKernelGGL((gemm_k<64,64,32,4,4,false,false,EPI_BIASRELU>), dim3(HID/64, BSZ/64), blk, 0, stream,
                       ftmp2, HID, w3, HID, ftmp1, HID, HID, b3, nullptr, 0, nullptr);
    hipLaunchKernelGGL(ln_k, dim3(BSZ), blk, 0, stream, ftmp1, g3, be3);
    hipLaunchKernelGGL((gemm_k<64,64,32,4,4,false,false,EPI_BIAS>), dim3(NV/64, BSZ/64), blk, 0, stream,
                       ftmp1, HID, wo, NV, z0, HID, NV, bo, nullptr, 0, nullptr);
    hipLaunchKernelGGL((gemm_k<64,64,32,4,4,true,false,EPI_NONE>), dim3(NV/64, BSZ/64), blk, 0, stream,
                       bp, MC, Wb, MC, fBias, MC, NV, nullptr, nullptr, 0, nullptr);
    hipLaunchKernelGGL((gemm_k<64,64,32,4,4,true,false,EPI_ADDMAT>), dim3(NV/64, BSZ/64), blk, 0, stream,
                       z0, NV, Wz, NV, out, NV, NV, nullptr, fBias, NV, nullptr);
    for (int j=1; j<=NITER; ++j){
      float* src = (j&1) ? out : fbuf1;
      float* dst = (j&1) ? fbuf1 : out;
      hipLaunchKernelGGL((gemm_k<64,64,32,4,4,true,true,EPI_ADDMAT>), dim3(NV/64, BSZ/64), blk, 0, stream,
                         src, NV, Wz, NV, dst, NV, NV, nullptr, fBias, NV, ffl);
      hipLaunchKernelGGL((gemm_k<32,64,32,2,4,true,false,EPI_EQ>), dim3(MC/64, BSZ/32), blk, 0, stream,
                         dst, NV, A, NV, feqp, NV, MC, nullptr, bp, MC, ffl);
      hipLaunchKernelGGL(check_k, dim3((MC + (NV-FREEN))/256), blk, 0, stream, feqp, dst, ffl+2, ffl, 8);
      hipLaunchKernelGGL(update_k, dim3(1), dim3(1), 0, stream, ffl);
    }
    hipLaunchKernelGGL(final_k, dim3((BSZ*NV)/256), blk, 0, stream, fbuf1, out, ffl);
  }

  (void)in_sizes; (void)n_in; (void)out_size; (void)ws_size;
}

// Round 11
// 3729.102 us; speedup vs baseline: 1.3829x; 1.3679x over previous
//
#include <hip/hip_runtime.h>
#include <math.h>

#define BSZ 256
#define NV  4096
#define MC  2048
#define HID 1024
#define FREEN 512
#define NITER 31
#define TOLF 1e-4f
#define EPSF 1e-6f
#define INV2048 4.8828125e-4f

typedef _Float16 half8 __attribute__((ext_vector_type(8)));
typedef float f32x16 __attribute__((ext_vector_type(16)));

enum { EPI_NONE=0, EPI_BIASRELU=1, EPI_BIAS=2, EPI_ADDMAT=3, EPI_EQ=4, EPI_SUBMAT=5 };

// Packed operand layout: matrix [R rows][K k] as tiles of 128 rows x 32 k.
// tile index = (row>>7)*(K/32) + (k>>5); within tile: oct*1024 + (row&127)*8 + (k&7)
// A staged tile is a LINEAR 8KB copy of one global tile.

// ---------------- f32 vector-ALU GEMM (fallback path only) ----------------
template<int BM,int BN,int BK,int TM,int TN,bool TB,bool RELUIN,int EPI>
__global__ __launch_bounds__(256)
void gemm_k(const float* __restrict__ X, int ldx,
            const float* __restrict__ W, int ldw,
            float* __restrict__ C,
            int K, int N,
            const float* __restrict__ bvec,
            const float* __restrict__ addm, int ldadd,
            const int* __restrict__ guard)
{
  if (guard && guard[0]) return;
  const int t = (int)threadIdx.x;
  const int m0 = (int)blockIdx.y*BM, n0 = (int)blockIdx.x*BN;
  __shared__ float As[BK][BM+4];
  __shared__ float Bs[BK][BN+4];
  constexpr int TX = BN/TN;
  const int tx = t % TX, ty = t / TX;
  constexpr int ALD = (BM*BK)/1024;
  constexpr int BLD = (BN*BK)/1024;
  float4 pa[ALD], pb[BLD];
  float acc[TM][TN];
  #pragma unroll
  for (int i=0;i<TM;i++)
    #pragma unroll
    for (int j=0;j<TN;j++) acc[i][j]=0.f;

  const int nk = K/BK;

  auto loadA = [&](int kt){
    const int k0 = kt*BK;
    const bool rl = RELUIN && (k0 >= FREEN);
    #pragma unroll
    for (int q=0;q<ALD;q++){
      const int idx = q*256 + t;
      const int r = idx/(BK/4), c4 = (idx%(BK/4))*4;
      float4 v = *reinterpret_cast<const float4*>(&X[(size_t)(m0+r)*ldx + k0 + c4]);
      if (rl){ v.x=fmaxf(v.x,0.f); v.y=fmaxf(v.y,0.f); v.z=fmaxf(v.z,0.f); v.w=fmaxf(v.w,0.f); }
      pa[q]=v;
    }
  };
  auto loadB = [&](int kt){
    const int k0 = kt*BK;
    #pragma unroll
    for (int q=0;q<BLD;q++){
      const int idx = q*256 + t;
      if (TB){
        const int r = idx/(BK/4), c4 = (idx%(BK/4))*4;
        pb[q] = *reinterpret_cast<const float4*>(&W[(size_t)(n0+r)*ldw + k0 + c4]);
      } else {
        const int r = idx/(BN/4), c4 = (idx%(BN/4))*4;
        pb[q] = *reinterpret_cast<const float4*>(&W[(size_t)(k0+r)*ldw + n0 + c4]);
      }
    }
  };
  auto stor = [&](){
    #pragma unroll
    for (int q=0;q<ALD;q++){
      const int idx = q*256 + t;
      const int r = idx/(BK/4), c4 = (idx%(BK/4))*4;
      As[c4+0][r]=pa[q].x; As[c4+1][r]=pa[q].y; As[c4+2][r]=pa[q].z; As[c4+3][r]=pa[q].w;
    }
    #pragma unroll
    for (int q=0;q<BLD;q++){
      const int idx = q*256 + t;
      if (TB){
        const int r = idx/(BK/4), c4 = (idx%(BK/4))*4;
        Bs[c4+0][r]=pb[q].x; Bs[c4+1][r]=pb[q].y; Bs[c4+2][r]=pb[q].z; Bs[c4+3][r]=pb[q].w;
      } else {
        const int r = idx/(BN/4), c4 = (idx%(BN/4))*4;
        *reinterpret_cast<float4*>(&Bs[r][c4]) = pb[q];
      }
    }
  };

  loadA(0); loadB(0);
  for (int kt=0; kt<nk; ++kt){
    __syncthreads();
    stor();
    __syncthreads();
    if (kt+1 < nk){ loadA(kt+1); loadB(kt+1); }
    #pragma unroll
    for (int kk=0; kk<BK; ++kk){
      float a[TM], b[TN];
      if constexpr (TM==4) *reinterpret_cast<float4*>(a) = *reinterpret_cast<const float4*>(&As[kk][ty*TM]);
      else                 *reinterpret_cast<float2*>(a) = *reinterpret_cast<const float2*>(&As[kk][ty*TM]);
      if constexpr (TN==4) *reinterpret_cast<float4*>(b) = *reinterpret_cast<const float4*>(&Bs[kk][tx*TN]);
      else                 *reinterpret_cast<float2*>(b) = *reinterpret_cast<const float2*>(&Bs[kk][tx*TN]);
      #pragma unroll
      for (int i=0;i<TM;i++)
        #pragma unroll
        for (int j=0;j<TN;j++)
          acc[i][j] = fmaf(a[i], b[j], acc[i][j]);
    }
  }

  if constexpr (EPI==EPI_EQ){
    float csum[TN];
    #pragma unroll
    for (int j=0;j<TN;j++) csum[j]=0.f;
    #pragma unroll
    for (int i=0;i<TM;i++){
      const int r = m0 + ty*TM + i;
      #pragma unroll
      for (int j=0;j<TN;j++){
        const int c = n0 + tx*TN + j;
        const float v = acc[i][j] - addm[(size_t)r*ldadd + c];
        csum[j] += fabsf(v);
      }
    }
    __syncthreads();
    float* red = &As[0][0];
    constexpr int RY = BM/TM;
    #pragma unroll
    for (int j=0;j<TN;j++) red[(tx*TN+j)*RY + ty] = csum[j];
    __syncthreads();
    if (t < BN){
      float s=0.f;
      #pragma unroll
      for (int y=0;y<RY;y++) s += red[t*RY + y];
      C[(size_t)blockIdx.y*N + n0 + t] = s;
    }
  } else {
    #pragma unroll
    for (int i=0;i<TM;i++){
      const int r = m0 + ty*TM + i;
      #pragma unroll
      for (int j=0;j<TN;j++){
        const int c = n0 + tx*TN + j;
        float v = acc[i][j];
        if constexpr (EPI==EPI_BIASRELU){ v += bvec[c]; v = fmaxf(v,0.f); }
        if constexpr (EPI==EPI_BIAS)    { v += bvec[c]; }
        if constexpr (EPI==EPI_ADDMAT)  { v += addm[(size_t)r*ldadd + c]; }
        if constexpr (EPI==EPI_SUBMAT)  { v -= addm[(size_t)r*ldadd + c]; }
        C[(size_t)r*N + c] = v;
      }
    }
  }
}

// ---------------- split helper ----------------
__device__ __forceinline__ void split_f32(float v, _Float16& h, _Float16& l){
  float hf = 0.f;
  _Float16 hh = (_Float16)0.f;
  if (fabsf(v) >= 6.103515625e-05f) { hh = (_Float16)v; hf = (float)hh; }
  h = hh;
  l = (_Float16)((v - hf) * 2048.0f);
}

// ---------------- LDS-tiled pack: f32 [R][K] -> packed pair ----------------
template<bool RELU>
__global__ __launch_bounds__(256)
void packpair_k(const float* __restrict__ src, _Float16* __restrict__ oh,
                _Float16* __restrict__ ol, int R, int K,
                const int* __restrict__ guard)
{
  if (guard && guard[0]) return;
  __shared__ float ts[128][33];
  const int t = (int)threadIdx.x;
  const int bid = (int)blockIdx.x;
  const int KT = K >> 5;
  const int rt = bid / KT, kt = bid % KT;
  const bool rl = RELU && (kt*32 >= FREEN);
  #pragma unroll
  for (int p=0;p<4;p++){
    const int row = p*32 + (t>>3);
    const int c4 = (t&7)*4;
    float4 v = *reinterpret_cast<const float4*>(&src[(size_t)(rt*128+row)*K + kt*32 + c4]);
    ts[row][c4+0]=v.x; ts[row][c4+1]=v.y; ts[row][c4+2]=v.z; ts[row][c4+3]=v.w;
  }
  __syncthreads();
  const int oct = t >> 6;
  const size_t tb = (size_t)bid*4096;
  #pragma unroll
  for (int rr=0; rr<2; ++rr){
    const int row = (t&63)*2 + rr;
    half8 hh, ll;
    #pragma unroll
    for (int j=0;j<8;j++){
      float v = ts[row][oct*8+j];
      if (rl) v = fmaxf(v, 0.f);
      _Float16 h,l; split_f32(v,h,l); hh[j]=h; ll[j]=l;
    }
    const size_t o = tb + (size_t)oct*1024 + row*8;
    *reinterpret_cast<half8*>(&oh[o]) = hh;
    if (ol) *reinterpret_cast<half8*>(&ol[o]) = ll;
  }
}

// ---------------- LDS-tiled transpose-pack: src [R][C] f32 -> packed pair of src^T ----
__global__ __launch_bounds__(256)
void trpackpair_k(const float* __restrict__ src, _Float16* __restrict__ oh,
                  _Float16* __restrict__ ol, int R, int C)
{
  __shared__ float ts[32][129];
  const int t = (int)threadIdx.x;
  const int bid = (int)blockIdx.x;
  const int KT = R >> 5;
  const int rt = bid / KT, kt = bid % KT;
  const int r0 = kt*32, c0 = rt*128;
  #pragma unroll
  for (int p=0;p<4;p++){
    const int sr = p*8 + (t>>5);
    const int sc4 = (t&31)*4;
    float4 v = *reinterpret_cast<const float4*>(&src[(size_t)(r0+sr)*C + c0 + sc4]);
    ts[sr][sc4+0]=v.x; ts[sr][sc4+1]=v.y; ts[sr][sc4+2]=v.z; ts[sr][sc4+3]=v.w;
  }
  __syncthreads();
  const int oct = t >> 6;
  const size_t tb = (size_t)bid*4096;
  #pragma unroll
  for (int rr=0; rr<2; ++rr){
    const int row = (t&63)*2 + rr;
    half8 hh, ll;
    #pragma unroll
    for (int j=0;j<8;j++){
      _Float16 h,l; split_f32(ts[oct*8+j][row], h, l); hh[j]=h; ll[j]=l;
    }
    const size_t o = tb + (size_t)oct*1024 + row*8;
    *reinterpret_cast<half8*>(&oh[o]) = hh;
    if (ol) *reinterpret_cast<half8*>(&ol[o]) = ll;
  }
}

// ---------------- fp16x2 pair-GEMM (prologue, packed operands) ----------------
__global__ __launch_bounds__(256)
void pairgemm_k(const _Float16* __restrict__ Ahg, const _Float16* __restrict__ Alg,
                const _Float16* __restrict__ Bhg, const _Float16* __restrict__ Blg,
                float* __restrict__ partial, int N, int K, int kzn,
                const int* __restrict__ guard)
{
  if (guard[0]) return;
  __shared__ _Float16 lds[2][8192];
  const int t = (int)threadIdx.x;
  const int lane = t & 63, wid = t >> 6;
  const int wr = wid >> 1, wc = wid & 1;
  const int ln = lane & 31, lg = lane >> 5;

  const int nt = (int)blockIdx.x, mt = (int)blockIdx.y, kz = (int)blockIdx.z;
  const int m0 = mt*128, n0 = nt*128;
  const int chunk = (3*K)/kzn;
  const int loExt = kz*chunk;
  const int nsteps = chunk/32;
  int ss = (2*K - loExt)/32;
  const int scaleStep = ss < 0 ? 0 : ss;
  const int KT = K >> 5;

  f32x16 acc[2][2];
  #pragma unroll
  for (int fm=0;fm<2;fm++)
    #pragma unroll
    for (int fn=0;fn<2;fn++)
      #pragma unroll
      for (int r=0;r<16;r++) acc[fm][fn][r] = 0.f;

  auto stage = [&](int i, int buf){
    const int gext = loExt + i*32;
    const _Float16* aB; const _Float16* bB; int kk;
    if (gext < K)         { aB = Ahg; bB = Blg; kk = gext; }
    else if (gext < 2*K)  { aB = Alg; bB = Bhg; kk = gext - K; }
    else                  { aB = Ahg; bB = Bhg; kk = gext - 2*K; }
    const int kt = kk >> 5;
    const _Float16* aT = aB + ((size_t)(mt*KT + kt))*4096;
    const _Float16* bT = bB + ((size_t)((n0>>7)*KT + kt))*4096;
    _Float16* base = &lds[buf][0];
    #pragma unroll
    for (int q=0;q<2;q++){
      const int W = q*4 + wid;
      __builtin_amdgcn_global_load_lds(
        (const __attribute__((address_space(1))) void*)(aT + W*512 + lane*8),
        (__attribute__((address_space(3))) void*)(base + W*512), 16, 0, 0);
      __builtin_amdgcn_global_load_lds(
        (const __attribute__((address_space(1))) void*)(bT + W*512 + lane*8),
        (__attribute__((address_space(3))) void*)(base + 4096 + W*512), 16, 0, 0);
    }
  };

  int cur = 0;
  stage(0, 0);
  __syncthreads();
  for (int i=0; i<nsteps; ++i){
    if (i+1 < nsteps) stage(i+1, cur^1);
    const _Float16* As = &lds[cur][0];
    const _Float16* Bs = &lds[cur][4096];
    half8 a[2][2], b[2][2];
    #pragma unroll
    for (int fm=0; fm<2; ++fm){
      const int row = wr*64 + fm*32 + ln;
      #pragma unroll
      for (int ks=0; ks<2; ++ks)
        a[fm][ks] = *reinterpret_cast<const half8*>(&As[(ks*2+lg)*1024 + row*8]);
    }
    #pragma unroll
    for (int fn=0; fn<2; ++fn){
      const int row = wc*64 + fn*32 + ln;
      #pragma unroll
      for (int ks=0; ks<2; ++ks)
        b[fn][ks] = *reinterpret_cast<const half8*>(&Bs[(ks*2+lg)*1024 + row*8]);
    }
    if (i == scaleStep){
      #pragma unroll
      for (int fm=0;fm<2;fm++)
        #pragma unroll
        for (int fn=0;fn<2;fn++)
          #pragma unroll
          for (int r=0;r<16;r++) acc[fm][fn][r] *= INV2048;
    }
    #pragma unroll
    for (int ks=0; ks<2; ++ks)
      #pragma unroll
      for (int fm=0; fm<2; ++fm)
        #pragma unroll
        for (int fn=0; fn<2; ++fn)
          acc[fm][fn] = __builtin_amdgcn_mfma_f32_32x32x16_f16(a[fm][ks], b[fn][ks], acc[fm][fn], 0, 0, 0);
    __syncthreads();
    cur ^= 1;
  }
  if (scaleStep >= nsteps){
    #pragma unroll
    for (int fm=0;fm<2;fm++)
      #pragma unroll
      for (int fn=0;fn<2;fn++)
        #pragma unroll
        for (int r=0;r<16;r++) acc[fm][fn][r] *= INV2048;
  }

  float* __restrict__ dst = partial + (size_t)kz*BSZ*N;
  #pragma unroll
  for (int fm=0; fm<2; ++fm)
    #pragma unroll
    for (int fn=0; fn<2; ++fn)
      #pragma unroll
      for (int r=0; r<16; ++r){
        const int row = (r&3) + 8*(r>>2) + 4*lg;
        const int gm = m0 + wr*64 + fm*32 + row;
        const int gn = n0 + wc*64 + fn*32 + ln;
        dst[(size_t)gm*N + gn] = acc[fm][fn][r];
      }
}

// sum of kz partials + f32 epilogue. grid (N/256, 16)
__global__ __launch_bounds__(256)
void sumn_k(const float* __restrict__ partial, int ng, int N,
            const float* __restrict__ bvec, const float* __restrict__ subm,
            int relu, float* __restrict__ outf, const int* __restrict__ guard)
{
  if (guard && guard[0]) return;
  const int c = blockIdx.x*256 + threadIdx.x;
  const int rb = blockIdx.y;
  const size_t SZ = (size_t)BSZ*N;
  for (int r=0; r<16; ++r){
    const size_t idx = (size_t)(rb*16+r)*N + c;
    float s = 0.f;
    for (int g=0; g<ng; ++g) s += partial[(size_t)g*SZ + idx];
    if (bvec) s += bvec[c];
    if (subm) s -= subm[idx];
    if (relu) s = fmaxf(s, 0.f);
    outf[idx] = s;
  }
}

// ---------------- fused loop MFMA kernel: packed operands, 3-segment single-acc,
// 3-buffer counted-vmcnt pipeline (raw s_barrier, never vmcnt(0) mid-loop) ----------------
// proj (L < 64*projKz): ext-K 12288 = [Ah*Wzl | Al*Wzh | Ah*Wzh], acc*=1/2048 at 8192.
// eq   (L >= nProj): Ah * Wbt, K=4096/eqKz.
// Every stage = 4 global_load_lds per wave (uniform G=4).
__global__ __launch_bounds__(256)
void fusedm_k(const _Float16* __restrict__ Ahg, const _Float16* __restrict__ Alg,
              const _Float16* __restrict__ Wzh, const _Float16* __restrict__ Wzl,
              const _Float16* __restrict__ Wbt,
              float* __restrict__ pp, float* __restrict__ ppe,
              int projKz, int eqKz, const int* __restrict__ guard)
{
  if (guard[0]) return;
  __shared__ _Float16 lds[3][8192];
  const int t = (int)threadIdx.x;
  const int lane = t & 63, wid = t >> 6;
  const int wr = wid >> 1, wc = wid & 1;
  const int ln = lane & 31, lg = lane >> 5;

  const int nwg = (int)gridDim.x;
  const int hw = (int)blockIdx.x;
  const int L = (hw & 7)*(nwg >> 3) + (hw >> 3);

  const int nProj = 64*projKz;
  const bool is_eq = L >= nProj;
  int kz, mt, nt, nsteps, scaleStep, loExt = 0, kbase = 0;
  if (!is_eq){
    mt = L & 1;
    kz = (L >> 1) % projKz;
    nt = L / (2*projKz);
    const int chunk = 12288 / projKz;
    loExt = kz * chunk;
    nsteps = chunk / 32;
    const int ss = (8192 - loExt) / 32;
    scaleStep = ss < 0 ? 0 : ss;
  } else {
    const int E = L - nProj;
    mt = E & 1;
    kz = (E >> 1) % eqKz;
    nt = E / (2*eqKz);
    nsteps = (NV/eqKz) / 32;
    kbase = kz*(NV/eqKz);
    scaleStep = -1;
  }
  const int m0 = mt*128, n0 = nt*128;
  const int KT = NV >> 5;

  f32x16 acc[2][2];
  #pragma unroll
  for (int fm=0;fm<2;fm++)
    #pragma unroll
    for (int fn=0;fn<2;fn++)
      #pragma unroll
      for (int r=0;r<16;r++) acc[fm][fn][r] = 0.f;

  auto stage = [&](int i, int buf){
    const _Float16 *aB, *bB; int kk;
    if (is_eq){
      aB = Ahg; bB = Wbt; kk = kbase + i*32;
    } else {
      const int gext = loExt + i*32;
      if (gext < 4096)      { aB = Ahg; bB = Wzl; kk = gext; }
      else if (gext < 8192) { aB = Alg; bB = Wzh; kk = gext - 4096; }
      else                  { aB = Ahg; bB = Wzh; kk = gext - 8192; }
    }
    const int kt = kk >> 5;
    const _Float16* aT = aB + ((size_t)(mt*KT + kt))*4096;
    const _Float16* bT = bB + ((size_t)((n0>>7)*KT + kt))*4096;
    _Float16* base = &lds[buf][0];
    #pragma unroll
    for (int q=0;q<2;q++){
      const int W = q*4 + wid;
      __builtin_amdgcn_global_load_lds(
        (const __attribute__((address_space(1))) void*)(aT + W*512 + lane*8),
        (__attribute__((address_space(3))) void*)(base + W*512), 16, 0, 0);
      __builtin_amdgcn_global_load_lds(
        (const __attribute__((address_space(1))) void*)(bT + W*512 + lane*8),
        (__attribute__((address_space(3))) void*)(base + 4096 + W*512), 16, 0, 0);
    }
  };

  // drain anything prior (guard load), then prime 2-deep
  asm volatile("s_waitcnt vmcnt(0)" ::: "memory");
  stage(0, 0);
  if (nsteps > 1) stage(1, 1);

  for (int i=0; i<nsteps; ++i){
    // wait for stage(i) only; stage(i+1) stays in flight across the barrier
    if (i+1 < nsteps) asm volatile("s_waitcnt vmcnt(4)" ::: "memory");
    else              asm volatile("s_waitcnt vmcnt(0)" ::: "memory");
    __builtin_amdgcn_sched_barrier(0);
    __builtin_amdgcn_s_barrier();          // all waves' stage(i) landed; all step i-1 reads done
    __builtin_amdgcn_sched_barrier(0);
    if (i+2 < nsteps) stage(i+2, (i+2)%3); // overwrites buf[(i-1)%3], readers finished
    const _Float16* As = &lds[i%3][0];
    const _Float16* Bs = &lds[i%3][4096];
    half8 a[2][2], b[2][2];
    #pragma unroll
    for (int fm=0; fm<2; ++fm){
      const int row = wr*64 + fm*32 + ln;
      #pragma unroll
      for (int ks=0; ks<2; ++ks)
        a[fm][ks] = *reinterpret_cast<const half8*>(&As[(ks*2+lg)*1024 + row*8]);
    }
    #pragma unroll
    for (int fn=0; fn<2; ++fn){
      const int row = wc*64 + fn*32 + ln;
      #pragma unroll
      for (int ks=0; ks<2; ++ks)
        b[fn][ks] = *reinterpret_cast<const half8*>(&Bs[(ks*2+lg)*1024 + row*8]);
    }
    if (!is_eq && i == scaleStep){
      #pragma unroll
      for (int fm=0;fm<2;fm++)
        #pragma unroll
        for (int fn=0;fn<2;fn++)
          #pragma unroll
          for (int r=0;r<16;r++) acc[fm][fn][r] *= INV2048;
    }
    #pragma unroll
    for (int ks=0; ks<2; ++ks)
      #pragma unroll
      for (int fm=0; fm<2; ++fm)
        #pragma unroll
        for (int fn=0; fn<2; ++fn)
          acc[fm][fn] = __builtin_amdgcn_mfma_f32_32x32x16_f16(a[fm][ks], b[fn][ks], acc[fm][fn], 0, 0, 0);
  }
  if (!is_eq && scaleStep >= nsteps){
    #pragma unroll
    for (int fm=0;fm<2;fm++)
      #pragma unroll
      for (int fn=0;fn<2;fn++)
        #pragma unroll
        for (int r=0;r<16;r++) acc[fm][fn][r] *= INV2048;
  }

  if (is_eq){
    float* __restrict__ dst = ppe + (size_t)kz*BSZ*MC;
    #pragma unroll
    for (int fm=0; fm<2; ++fm)
      #pragma unroll
      for (int fn=0; fn<2; ++fn)
        #pragma unroll
        for (int r=0; r<16; ++r){
          const int row = (r&3) + 8*(r>>2) + 4*lg;
          const int gm = m0 + wr*64 + fm*32 + row;
          const int gn = n0 + wc*64 + fn*32 + ln;
          dst[(size_t)gm*MC + gn] = acc[fm][fn][r];
        }
  } else {
    float* __restrict__ dst = pp + (size_t)kz*BSZ*NV;
    #pragma unroll
    for (int fm=0; fm<2; ++fm)
      #pragma unroll
      for (int fn=0; fn<2; ++fn)
        #pragma unroll
        for (int r=0; r<16; ++r){
          const int row = (r&3) + 8*(r>>2) + 4*lg;
          const int gm = m0 + wr*64 + fm*32 + row;
          const int gn = n0 + wc*64 + fn*32 + ln;
          dst[(size_t)gm*NV + gn] = acc[fm][fn][r];
        }
  }
}

// combine + ineq + relu-split-pack (coalesced). grid = (BSZ/128)*(NV/32)
__global__ __launch_bounds__(256)
void combinep_k(const float* __restrict__ pp, int ng, const float* __restrict__ BiasM,
                float* __restrict__ zout, _Float16* __restrict__ rzh,
                _Float16* __restrict__ rzl, float* __restrict__ ineqpart,
                const int* __restrict__ guard)
{
  if (guard[0]) return;
  __shared__ float ts[128][33];
  const int t = (int)threadIdx.x;
  const int bid = (int)blockIdx.x;
  const int rt = bid >> 7, kt = bid & 127;
  const size_t SZ = (size_t)BSZ*NV;
  #pragma unroll
  for (int p=0;p<4;p++){
    const int row = p*32 + (t>>3);
    const int c4 = (t&7)*4;
    const size_t idx = (size_t)(rt*128+row)*NV + kt*32 + c4;
    float4 z = *reinterpret_cast<const float4*>(&BiasM[idx]);
    for (int g=0; g<ng; ++g){
      const float4 v = *reinterpret_cast<const float4*>(&pp[(size_t)g*SZ + idx]);
      z.x+=v.x; z.y+=v.y; z.z+=v.z; z.w+=v.w;
    }
    *reinterpret_cast<float4*>(&zout[idx]) = z;
    ts[row][c4+0]=z.x; ts[row][c4+1]=z.y; ts[row][c4+2]=z.z; ts[row][c4+3]=z.w;
  }
  __syncthreads();
  {
    const int g = t >> 5, c = t & 31;
    float s = 0.f;
    #pragma unroll
    for (int r=0;r<16;r++) s += fmaxf(-ts[g*16+r][c], 0.f);
    ineqpart[(size_t)(rt*8+g)*NV + kt*32 + c] = s;
  }
  const bool rl = (kt*32 >= FREEN);
  const int oct = t >> 6;
  const size_t tb = (size_t)bid*4096;
  #pragma unroll
  for (int rr=0; rr<2; ++rr){
    const int row = (t&63)*2 + rr;
    half8 hh, ll;
    #pragma unroll
    for (int j=0;j<8;j++){
      float v = ts[row][oct*8+j];
      if (rl) v = fmaxf(v, 0.f);
      _Float16 h,l; split_f32(v,h,l); hh[j]=h; ll[j]=l;
    }
    const size_t o = tb + (size_t)oct*1024 + row*8;
    *reinterpret_cast<half8*>(&rzh[o]) = hh;
    *reinterpret_cast<half8*>(&rzl[o]) = ll;
  }
}

__global__ __launch_bounds__(256)
void eqredN_k(const float* __restrict__ ppe, const float* __restrict__ BiasATmB,
              float* __restrict__ eqpart16, int ng, const int* __restrict__ guard)
{
  if (guard[0]) return;
  const int c = blockIdx.x*256 + threadIdx.x;
  const int rb = blockIdx.y;
  const size_t SE = (size_t)BSZ*MC;
  float s = 0.f;
  for (int r=0; r<16; ++r){
    const size_t idx = (size_t)(rb*16+r)*MC + c;
    float acc = 0.f;
    for (int g=0; g<ng; ++g) acc += ppe[(size_t)g*SE + idx];
    s += fabsf(BiasATmB[idx] + EPSF*acc);
  }
  eqpart16[(size_t)rb*MC + c] = s;
}

__global__ __launch_bounds__(256)
void check3_k(const float* __restrict__ eqpart16, const float* __restrict__ ineqpart,
              int* __restrict__ viol, const int* __restrict__ done)
{
  if (done[0]) return;
  const int id = blockIdx.x*256 + threadIdx.x;
  bool bad;
  if (id < MC){
    float s = 0.f;
    #pragma unroll
    for (int g=0; g<16; g++) s += eqpart16[(size_t)g*MC + id];
    bad = (s*(1.f/(float)BSZ) > TOLF);
  } else {
    const int c = FREEN + (id - MC);
    float s = 0.f;
    #pragma unroll
    for (int g=0; g<16; g++) s += ineqpart[(size_t)g*NV + c];
    bad = (s*(1.f/(float)BSZ) > TOLF);
  }
  if (bad) atomicAdd(viol, 1);
}

// ---------------- LayerNorm ----------------
__global__ __launch_bounds__(256)
void ln_k(float* __restrict__ x, const float* __restrict__ g, const float* __restrict__ b)
{
  const int row = blockIdx.x, t = threadIdx.x;
  float4 v = *reinterpret_cast<const float4*>(&x[(size_t)row*HID + t*4]);
  __shared__ float sm[256];
  sm[t] = v.x+v.y+v.z+v.w;
  __syncthreads();
  for (int st=128; st>0; st>>=1){ if (t<st) sm[t]+=sm[t+st]; __syncthreads(); }
  const float mu = sm[0]*(1.f/(float)HID);
  __syncthreads();
  const float dx=v.x-mu, dy=v.y-mu, dz=v.z-mu, dw=v.w-mu;
  sm[t] = dx*dx+dy*dy+dz*dz+dw*dw;
  __syncthreads();
  for (int st=128; st>0; st>>=1){ if (t<st) sm[t]+=sm[t+st]; __syncthreads(); }
  const float inv = 1.f/sqrtf(sm[0]*(1.f/(float)HID) + 1e-5f);
  const int c = t*4;
  const float4 gv = *reinterpret_cast<const float4*>(&g[c]);
  const float4 bv = *reinterpret_cast<const float4*>(&b[c]);
  float4 o;
  o.x = dx*inv*gv.x + bv.x; o.y = dy*inv*gv.y + bv.y;
  o.z = dz*inv*gv.z + bv.z; o.w = dw*inv*gv.w + bv.w;
  *reinterpret_cast<float4*>(&x[(size_t)row*HID + c]) = o;
}

// ---------------- flags / fallback machinery ----------------
__global__ __launch_bounds__(256)
void check_k(const float* __restrict__ eqpart, const float* __restrict__ znew,
             int* __restrict__ viol, const int* __restrict__ done, int ngroups)
{
  if (done[0]) return;
  const int id = blockIdx.x*256 + threadIdx.x;
  bool bad;
  if (id < MC){
    float s = 0.f;
    for (int g=0; g<ngroups; g++) s += eqpart[g*MC + id];
    bad = (s*(1.f/(float)BSZ) > TOLF);
  } else {
    const int c = FREEN + (id - MC);
    float s = 0.f;
    for (int r=0; r<BSZ; r++){
      const float v = znew[(size_t)r*NV + c];
      s += (v < 0.f) ? -v : 0.f;
    }
    bad = (s*(1.f/(float)BSZ) > TOLF);
  }
  if (bad) atomicAdd(viol, 1);
}

__global__ void init_k(int* flags){ flags[0]=0; flags[1]=0; flags[2]=0; }

__global__ void update_k(int* flags){
  if (!flags[0]){ flags[1] += 1; if (flags[2]==0) flags[0]=1; }
  flags[2] = 0;
}

__global__ __launch_bounds__(256)
void final_k(const float* __restrict__ buf1, float* __restrict__ out, const int* __restrict__ flags)
{
  const int i = blockIdx.x*256 + threadIdx.x;
  const int k = flags[1];
  if ((k & 1) && i < BSZ*NV) out[i] = buf1[i];
  if (i == 0) out[2*BSZ*NV] = (float)k;
}

__global__ void finalp_k(float* __restrict__ out, const int* __restrict__ flags)
{
  out[2*(size_t)BSZ*NV] = (float)flags[1];
}

// ---------------- host launch ----------------
extern "C" void kernel_launch(void* const* d_in, const int* in_sizes, int n_in,
                              void* d_out, int out_size, void* d_ws, size_t ws_size,
                              hipStream_t stream)
{
  const float* bp  = (const float*)d_in[0];
  const float* w1  = (const float*)d_in[1];
  const float* b1  = (const float*)d_in[2];
  const float* g1  = (const float*)d_in[3];
  const float* be1 = (const float*)d_in[4];
  const float* w2  = (const float*)d_in[5];
  const float* b2  = (const float*)d_in[6];
  const float* g2  = (const float*)d_in[7];
  const float* be2 = (const float*)d_in[8];
  const float* w3  = (const float*)d_in[9];
  const float* b3  = (const float*)d_in[10];
  const float* g3  = (const float*)d_in[11];
  const float* be3 = (const float*)d_in[12];
  const float* wo  = (const float*)d_in[13];
  const float* bo  = (const float*)d_in[14];
  const float* A   = (const float*)d_in[15];
  const float* Wz  = (const float*)d_in[16];
  const float* Wb  = (const float*)d_in[17];

  float* out  = (float*)d_out;
  float* z0   = out + (size_t)BSZ*NV;
  float* zbuf = out;

  auto layout_need = [&](int PKZ_, int EKZ_)->size_t{
    size_t f = (size_t)1048576*(1+PKZ_) + (size_t)524288*EKZ_ + 524288 + 32768 + 65536 + 16;
    size_t h = (size_t)NV*NV*2 + (size_t)MC*NV + (size_t)2*BSZ*NV;
    return f*4 + h*2;
  };
  int PKZ = 8, EKZ = 4;
  if (ws_size < layout_need(8,4)) { PKZ = 4; EKZ = 2; }
  const bool fp16path = (ws_size >= layout_need(PKZ, EKZ));
  const int KZBIG = (PKZ == 8) ? 6 : 4;

  float* ws_f = (float*)d_ws;
  float* BiasM    = ws_f;
  float* pp       = BiasM + (size_t)BSZ*NV;
  float* ppe      = pp + (size_t)PKZ*BSZ*NV;
  float* BiasATmB = ppe + (size_t)EKZ*BSZ*MC;
  float* eqpart16 = BiasATmB + (size_t)BSZ*MC;
  float* ineqpart = eqpart16 + (size_t)16*MC;
  int*   flags    = (int*)(ineqpart + (size_t)16*NV);
  _Float16* Wzh = (_Float16*)(flags + 16);
  _Float16* Wzl = Wzh + (size_t)NV*NV;
  _Float16* Wbt = Wzl + (size_t)NV*NV;
  _Float16* rzh = Wbt + (size_t)MC*NV;
  _Float16* rzl = rzh + (size_t)BSZ*NV;

  _Float16* PBh = Wzh;
  _Float16* PBl = Wzh + (size_t)NV*NV/2;
  _Float16* bph = Wzl;
  _Float16* bpl = bph + (size_t)BSZ*MC;
  float*    hbuf = (float*)(bpl + (size_t)BSZ*MC);
  _Float16* hph = (_Float16*)(hbuf + (size_t)BSZ*HID);
  _Float16* hpl = hph + (size_t)BSZ*HID;
  _Float16* Bsh = hpl + (size_t)BSZ*HID;
  _Float16* Bsl = Bsh + (size_t)BSZ*NV;
  _Float16* zh0 = rzh;
  _Float16* zl0 = rzl;

  const dim3 blk(256);

  if (fp16path){
    hipLaunchKernelGGL(init_k, dim3(1), dim3(1), 0, stream, flags);

    // ---- MLP via pair-MFMA (packed operands) ----
    hipLaunchKernelGGL((packpair_k<false>), dim3((BSZ/128)*(MC/32)), blk, 0, stream, bp, bph, bpl, BSZ, MC, nullptr);
    hipLaunchKernelGGL(trpackpair_k, dim3((HID/128)*(MC/32)), blk, 0, stream, w1, PBh, PBl, MC, HID);
    hipLaunchKernelGGL(pairgemm_k, dim3(HID/128, 2, 8), blk, 0, stream, bph, bpl, PBh, PBl, pp, HID, MC, 8, flags);
    hipLaunchKernelGGL(sumn_k, dim3(HID/256, 16), blk, 0, stream, pp, 8, HID, b1, nullptr, 1, hbuf, flags);
    hipLaunchKernelGGL(ln_k, dim3(BSZ), blk, 0, stream, hbuf, g1, be1);
    hipLaunchKernelGGL((packpair_k<false>), dim3((BSZ/128)*(HID/32)), blk, 0, stream, hbuf, hph, hpl, BSZ, HID, nullptr);

    hipLaunchKernelGGL(trpackpair_k, dim3((HID/128)*(HID/32)), blk, 0, stream, w2, PBh, PBl, HID, HID);
    hipLaunchKernelGGL(pairgemm_k, dim3(HID/128, 2, 8), blk, 0, stream, hph, hpl, PBh, PBl, pp, HID, HID, 8, flags);
    hipLaunchKernelGGL(sumn_k, dim3(HID/256, 16), blk, 0, stream, pp, 8, HID, b2, nullptr, 1, hbuf, flags);
    hipLaunchKernelGGL(ln_k, dim3(BSZ), blk, 0, stream, hbuf, g2, be2);
    hipLaunchKernelGGL((packpair_k<false>), dim3((BSZ/128)*(HID/32)), blk, 0, stream, hbuf, hph, hpl, BSZ, HID, nullptr);

    hipLaunchKernelGGL(trpackpair_k, dim3((HID/128)*(HID/32)), blk, 0, stream, w3, PBh, PBl, HID, HID);
    hipLaunchKernelGGL(pairgemm_k, dim3(HID/128, 2, 8), blk, 0, stream, hph, hpl, PBh, PBl, pp, HID, HID, 8, flags);
    hipLaunchKernelGGL(sumn_k, dim3(HID/256, 16), blk, 0, stream, pp, 8, HID, b3, nullptr, 1, hbuf, flags);
    hipLaunchKernelGGL(ln_k, dim3(BSZ), blk, 0, stream, hbuf, g3, be3);
    hipLaunchKernelGGL((packpair_k<false>), dim3((BSZ/128)*(HID/32)), blk, 0, stream, hbuf, hph, hpl, BSZ, HID, nullptr);

    // z0 = h3 @ wo + bo
    hipLaunchKernelGGL(trpackpair_k, dim3((NV/128)*(HID/32)), blk, 0, stream, wo, PBh, PBl, HID, NV);
    hipLaunchKernelGGL(pairgemm_k, dim3(NV/128, 2, KZBIG), blk, 0, stream, hph, hpl, PBh, PBl, pp, NV, HID, KZBIG, flags);
    hipLaunchKernelGGL(sumn_k, dim3(NV/256, 16), blk, 0, stream, pp, KZBIG, NV, bo, nullptr, 0, z0, flags);
    hipLaunchKernelGGL((packpair_k<false>), dim3((BSZ/128)*(NV/32)), blk, 0, stream, z0, zh0, zl0, BSZ, NV, nullptr);

    // Bias = bp @ WbProj^T
    hipLaunchKernelGGL((packpair_k<false>), dim3((NV/128)*(MC/32)), blk, 0, stream, Wb, PBh, PBl, NV, MC, nullptr);
    hipLaunchKernelGGL(pairgemm_k, dim3(NV/128, 2, KZBIG), blk, 0, stream, bph, bpl, PBh, PBl, pp, NV, MC, KZBIG, flags);
    hipLaunchKernelGGL(sumn_k, dim3(NV/256, 16), blk, 0, stream, pp, KZBIG, NV, nullptr, nullptr, 0, BiasM, flags);
    hipLaunchKernelGGL((packpair_k<false>), dim3((BSZ/128)*(NV/32)), blk, 0, stream, BiasM, Bsh, Bsl, BSZ, NV, nullptr);

    // BiasATmB = Bias @ A^T - bp
    hipLaunchKernelGGL((packpair_k<false>), dim3((MC/128)*(NV/32)), blk, 0, stream, A, PBh, PBl, MC, NV, nullptr);
    hipLaunchKernelGGL(pairgemm_k, dim3(MC/128, 2, KZBIG), blk, 0, stream, Bsh, Bsl, PBh, PBl, pp, MC, NV, KZBIG, flags);
    hipLaunchKernelGGL(sumn_k, dim3(MC/256, 16), blk, 0, stream, pp, KZBIG, MC, nullptr, bp, 0, BiasATmB, flags);

    // loop constants
    hipLaunchKernelGGL(trpackpair_k, dim3((MC/128)*(NV/32)), blk, 0, stream, Wb, Wbt, (_Float16*)nullptr, NV, MC);
    hipLaunchKernelGGL((packpair_k<false>), dim3((NV/128)*(NV/32)), blk, 0, stream, Wz, Wzh, Wzl, NV, NV, nullptr);

    // bootstrap: z_init = Bias + z0 @ Wp (proj blocks only)
    hipLaunchKernelGGL(fusedm_k, dim3(64*PKZ), blk, 0, stream,
                       zh0, zl0, Wzh, Wzl, Wbt, pp, ppe, PKZ, 1, flags);
    hipLaunchKernelGGL(combinep_k, dim3((BSZ/128)*(NV/32)), blk, 0, stream,
                       pp, PKZ, BiasM, zbuf, rzh, rzl, ineqpart, flags);

    const int loopGrid = 64*PKZ + 32*EKZ;
    for (int j=1; j<=NITER; ++j){
      hipLaunchKernelGGL(fusedm_k, dim3(loopGrid), blk, 0, stream,
                         rzh, rzl, Wzh, Wzl, Wbt, pp, ppe, PKZ, EKZ, flags);
      hipLaunchKernelGGL(combinep_k, dim3((BSZ/128)*(NV/32)), blk, 0, stream,
                         pp, PKZ, BiasM, zbuf, rzh, rzl, ineqpart, flags);
      hipLaunchKernelGGL(eqredN_k, dim3(MC/256, 16), blk, 0, stream,
                         ppe, BiasATmB, eqpart16, EKZ, flags);
      hipLaunchKernelGGL(check3_k, dim3((MC + (NV-FREEN))/256), blk, 0, stream,
                         eqpart16, ineqpart, flags+2, flags);
      hipLaunchKernelGGL(update_k, dim3(1), dim3(1), 0, stream, flags);
    }
    hipLaunchKernelGGL(finalp_k, dim3(1), dim3(1), 0, stream, out, flags);
  } else {
    // fallback: proven f32 loop
    float* ftmp1 = ws_f;
    float* ftmp2 = ftmp1 + (size_t)BSZ*HID;
    float* fBias = ftmp2 + (size_t)BSZ*HID;
    float* fbuf1 = fBias + (size_t)BSZ*NV;
    float* feqp  = fbuf1 + (size_t)BSZ*NV;
    int*   ffl   = (int*)(feqp + 8*MC);

    hipLaunchKernelGGL(init_k, dim3(1), dim3(1), 0, stream, ffl);
    hipLaunchKernelGGL((gemm_k<64,64,32,4,4,false,false,EPI_BIASRELU>), dim3(HID/64, BSZ/64), blk, 0, stream,
                       bp, MC, w1, HID, ftmp1, MC, HID, b1, nullptr, 0, nullptr);
    hipLaunchKernelGGL(ln_k, dim3(BSZ), blk, 0, stream, ftmp1, g1, be1);
    hipLaunchKernelGGL((gemm_k<64,64,32,4,4,false,false,EPI_BIASRELU>), dim3(HID/64, BSZ/64), blk, 0, stream,
                       ftmp1, HID, w2, HID, ftmp2, HID, HID, b2, nullptr, 0, nullptr);
    hipLaunchKernelGGL(ln_k, dim3(BSZ), blk, 0, stream, ftmp2, g2, be2);
    hipLaunchKernelGGL((gemm_k<64,64,32,4,4,false,false,EPI_BIASRELU>), dim3(HID/64, BSZ/64), blk, 0, stream,
                       ftmp2, HID, w3, HID, ftmp1, HID, HID, b3, nullptr, 0, nullptr);
    hipLaunchKernelGGL(ln_k, dim3(BSZ), blk, 0, stream, ftmp1, g3, be3);
    hipLaunchKernelGGL((gemm_k<64,64,32,4,4,false,false,EPI_BIAS>), dim3(NV/64, BSZ/64), blk, 0, stream,
                       ftmp1, HID, wo, NV, z0, HID, NV, bo, nullptr, 0, nullptr);
    hipLaunchKernelGGL((gemm_k<64,64,32,4,4,true,false,EPI_NONE>), dim3(NV/64, BSZ/64), blk, 0, stream,
                       bp, MC, Wb, MC, fBias, MC, NV, nullptr, nullptr, 0, nullptr);
    hipLaunchKernelGGL((gemm_k<64,64,32,4,4,true,false,EPI_ADDMAT>), dim3(NV/64, BSZ/64), blk, 0, stream,
                       z0, NV, Wz, NV, out, NV, NV, nullptr, fBias, NV, nullptr);
    for (int j=1; j<=NITER; ++j){
      float* src = (j&1) ? out : fbuf1;
      float* dst = (j&1) ? fbuf1 : out;
      hipLaunchKernelGGL((gemm_k<64,64,32,4,4,true,true,EPI_ADDMAT>), dim3(NV/64, BSZ/64), blk, 0, stream,
                         src, NV, Wz, NV, dst, NV, NV, nullptr, fBias, NV, ffl);
      hipLaunchKernelGGL((gemm_k<32,64,32,2,4,true,false,EPI_EQ>), dim3(MC/64, BSZ/32), blk, 0, stream,
                         dst, NV, A, NV, feqp, NV, MC, nullptr, bp, MC, ffl);
      hipLaunchKernelGGL(check_k, dim3((MC + (NV-FREEN))/256), blk, 0, stream, feqp, dst, ffl+2, ffl, 8);
      hipLaunchKernelGGL(update_k, dim3(1), dim3(1), 0, stream, ffl);
    }
    hipLaunchKernelGGL(final_k, dim3((BSZ*NV)/256), blk, 0, stream, fbuf1, out, ffl);
  }

  (void)in_sizes; (void)n_in; (void)out_size; (void)ws_size;
}

// Round 12
// 3105.995 us; speedup vs baseline: 1.6604x; 1.2006x over previous
//
#include <hip/hip_runtime.h>
#include <math.h>

#define BSZ 256
#define NV  4096
#define MC  2048
#define HID 1024
#define FREEN 512
#define NITER 31
#define TOLF 1e-4f
#define EPSF 1e-6f
#define INV2048 4.8828125e-4f

typedef _Float16 half8 __attribute__((ext_vector_type(8)));
typedef float f32x16 __attribute__((ext_vector_type(16)));

enum { EPI_NONE=0, EPI_BIASRELU=1, EPI_BIAS=2, EPI_ADDMAT=3, EPI_EQ=4, EPI_SUBMAT=5 };

// Packed operand layout: matrix [R rows][K k] as tiles of 128 rows x 32 k.
// tile index = (row>>7)*(K/32) + (k>>5); within tile: oct*1024 + (row&127)*8 + (k&7)
// A staged tile is a LINEAR 8KB copy of one global tile.

// ---------------- f32 vector-ALU GEMM (fallback path only) ----------------
template<int BM,int BN,int BK,int TM,int TN,bool TB,bool RELUIN,int EPI>
__global__ __launch_bounds__(256)
void gemm_k(const float* __restrict__ X, int ldx,
            const float* __restrict__ W, int ldw,
            float* __restrict__ C,
            int K, int N,
            const float* __restrict__ bvec,
            const float* __restrict__ addm, int ldadd,
            const int* __restrict__ guard)
{
  if (guard && guard[0]) return;
  const int t = (int)threadIdx.x;
  const int m0 = (int)blockIdx.y*BM, n0 = (int)blockIdx.x*BN;
  __shared__ float As[BK][BM+4];
  __shared__ float Bs[BK][BN+4];
  constexpr int TX = BN/TN;
  const int tx = t % TX, ty = t / TX;
  constexpr int ALD = (BM*BK)/1024;
  constexpr int BLD = (BN*BK)/1024;
  float4 pa[ALD], pb[BLD];
  float acc[TM][TN];
  #pragma unroll
  for (int i=0;i<TM;i++)
    #pragma unroll
    for (int j=0;j<TN;j++) acc[i][j]=0.f;

  const int nk = K/BK;

  auto loadA = [&](int kt){
    const int k0 = kt*BK;
    const bool rl = RELUIN && (k0 >= FREEN);
    #pragma unroll
    for (int q=0;q<ALD;q++){
      const int idx = q*256 + t;
      const int r = idx/(BK/4), c4 = (idx%(BK/4))*4;
      float4 v = *reinterpret_cast<const float4*>(&X[(size_t)(m0+r)*ldx + k0 + c4]);
      if (rl){ v.x=fmaxf(v.x,0.f); v.y=fmaxf(v.y,0.f); v.z=fmaxf(v.z,0.f); v.w=fmaxf(v.w,0.f); }
      pa[q]=v;
    }
  };
  auto loadB = [&](int kt){
    const int k0 = kt*BK;
    #pragma unroll
    for (int q=0;q<BLD;q++){
      const int idx = q*256 + t;
      if (TB){
        const int r = idx/(BK/4), c4 = (idx%(BK/4))*4;
        pb[q] = *reinterpret_cast<const float4*>(&W[(size_t)(n0+r)*ldw + k0 + c4]);
      } else {
        const int r = idx/(BN/4), c4 = (idx%(BN/4))*4;
        pb[q] = *reinterpret_cast<const float4*>(&W[(size_t)(k0+r)*ldw + n0 + c4]);
      }
    }
  };
  auto stor = [&](){
    #pragma unroll
    for (int q=0;q<ALD;q++){
      const int idx = q*256 + t;
      const int r = idx/(BK/4), c4 = (idx%(BK/4))*4;
      As[c4+0][r]=pa[q].x; As[c4+1][r]=pa[q].y; As[c4+2][r]=pa[q].z; As[c4+3][r]=pa[q].w;
    }
    #pragma unroll
    for (int q=0;q<BLD;q++){
      const int idx = q*256 + t;
      if (TB){
        const int r = idx/(BK/4), c4 = (idx%(BK/4))*4;
        Bs[c4+0][r]=pb[q].x; Bs[c4+1][r]=pb[q].y; Bs[c4+2][r]=pb[q].z; Bs[c4+3][r]=pb[q].w;
      } else {
        const int r = idx/(BN/4), c4 = (idx%(BN/4))*4;
        *reinterpret_cast<float4*>(&Bs[r][c4]) = pb[q];
      }
    }
  };

  loadA(0); loadB(0);
  for (int kt=0; kt<nk; ++kt){
    __syncthreads();
    stor();
    __syncthreads();
    if (kt+1 < nk){ loadA(kt+1); loadB(kt+1); }
    #pragma unroll
    for (int kk=0; kk<BK; ++kk){
      float a[TM], b[TN];
      if constexpr (TM==4) *reinterpret_cast<float4*>(a) = *reinterpret_cast<const float4*>(&As[kk][ty*TM]);
      else                 *reinterpret_cast<float2*>(a) = *reinterpret_cast<const float2*>(&As[kk][ty*TM]);
      if constexpr (TN==4) *reinterpret_cast<float4*>(b) = *reinterpret_cast<const float4*>(&Bs[kk][tx*TN]);
      else                 *reinterpret_cast<float2*>(b) = *reinterpret_cast<const float2*>(&Bs[kk][tx*TN]);
      #pragma unroll
      for (int i=0;i<TM;i++)
        #pragma unroll
        for (int j=0;j<TN;j++)
          acc[i][j] = fmaf(a[i], b[j], acc[i][j]);
    }
  }

  if constexpr (EPI==EPI_EQ){
    float csum[TN];
    #pragma unroll
    for (int j=0;j<TN;j++) csum[j]=0.f;
    #pragma unroll
    for (int i=0;i<TM;i++){
      const int r = m0 + ty*TM + i;
      #pragma unroll
      for (int j=0;j<TN;j++){
        const int c = n0 + tx*TN + j;
        const float v = acc[i][j] - addm[(size_t)r*ldadd + c];
        csum[j] += fabsf(v);
      }
    }
    __syncthreads();
    float* red = &As[0][0];
    constexpr int RY = BM/TM;
    #pragma unroll
    for (int j=0;j<TN;j++) red[(tx*TN+j)*RY + ty] = csum[j];
    __syncthreads();
    if (t < BN){
      float s=0.f;
      #pragma unroll
      for (int y=0;y<RY;y++) s += red[t*RY + y];
      C[(size_t)blockIdx.y*N + n0 + t] = s;
    }
  } else {
    #pragma unroll
    for (int i=0;i<TM;i++){
      const int r = m0 + ty*TM + i;
      #pragma unroll
      for (int j=0;j<TN;j++){
        const int c = n0 + tx*TN + j;
        float v = acc[i][j];
        if constexpr (EPI==EPI_BIASRELU){ v += bvec[c]; v = fmaxf(v,0.f); }
        if constexpr (EPI==EPI_BIAS)    { v += bvec[c]; }
        if constexpr (EPI==EPI_ADDMAT)  { v += addm[(size_t)r*ldadd + c]; }
        if constexpr (EPI==EPI_SUBMAT)  { v -= addm[(size_t)r*ldadd + c]; }
        C[(size_t)r*N + c] = v;
      }
    }
  }
}

// ---------------- split helper ----------------
__device__ __forceinline__ void split_f32(float v, _Float16& h, _Float16& l){
  float hf = 0.f;
  _Float16 hh = (_Float16)0.f;
  if (fabsf(v) >= 6.103515625e-05f) { hh = (_Float16)v; hf = (float)hh; }
  h = hh;
  l = (_Float16)((v - hf) * 2048.0f);
}

// ---------------- LDS-tiled pack: f32 [R][K] -> packed pair ----------------
template<bool RELU>
__global__ __launch_bounds__(256)
void packpair_k(const float* __restrict__ src, _Float16* __restrict__ oh,
                _Float16* __restrict__ ol, int R, int K,
                const int* __restrict__ guard)
{
  if (guard && guard[0]) return;
  __shared__ float ts[128][33];
  const int t = (int)threadIdx.x;
  const int bid = (int)blockIdx.x;
  const int KT = K >> 5;
  const int rt = bid / KT, kt = bid % KT;
  const bool rl = RELU && (kt*32 >= FREEN);
  #pragma unroll
  for (int p=0;p<4;p++){
    const int row = p*32 + (t>>3);
    const int c4 = (t&7)*4;
    float4 v = *reinterpret_cast<const float4*>(&src[(size_t)(rt*128+row)*K + kt*32 + c4]);
    ts[row][c4+0]=v.x; ts[row][c4+1]=v.y; ts[row][c4+2]=v.z; ts[row][c4+3]=v.w;
  }
  __syncthreads();
  const int oct = t >> 6;
  const size_t tb = (size_t)bid*4096;
  #pragma unroll
  for (int rr=0; rr<2; ++rr){
    const int row = (t&63)*2 + rr;
    half8 hh, ll;
    #pragma unroll
    for (int j=0;j<8;j++){
      float v = ts[row][oct*8+j];
      if (rl) v = fmaxf(v, 0.f);
      _Float16 h,l; split_f32(v,h,l); hh[j]=h; ll[j]=l;
    }
    const size_t o = tb + (size_t)oct*1024 + row*8;
    *reinterpret_cast<half8*>(&oh[o]) = hh;
    if (ol) *reinterpret_cast<half8*>(&ol[o]) = ll;
  }
}

// ---------------- LDS-tiled transpose-pack: src [R][C] f32 -> packed pair of src^T ----
__global__ __launch_bounds__(256)
void trpackpair_k(const float* __restrict__ src, _Float16* __restrict__ oh,
                  _Float16* __restrict__ ol, int R, int C)
{
  __shared__ float ts[32][129];
  const int t = (int)threadIdx.x;
  const int bid = (int)blockIdx.x;
  const int KT = R >> 5;
  const int rt = bid / KT, kt = bid % KT;
  const int r0 = kt*32, c0 = rt*128;
  #pragma unroll
  for (int p=0;p<4;p++){
    const int sr = p*8 + (t>>5);
    const int sc4 = (t&31)*4;
    float4 v = *reinterpret_cast<const float4*>(&src[(size_t)(r0+sr)*C + c0 + sc4]);
    ts[sr][sc4+0]=v.x; ts[sr][sc4+1]=v.y; ts[sr][sc4+2]=v.z; ts[sr][sc4+3]=v.w;
  }
  __syncthreads();
  const int oct = t >> 6;
  const size_t tb = (size_t)bid*4096;
  #pragma unroll
  for (int rr=0; rr<2; ++rr){
    const int row = (t&63)*2 + rr;
    half8 hh, ll;
    #pragma unroll
    for (int j=0;j<8;j++){
      _Float16 h,l; split_f32(ts[oct*8+j][row], h, l); hh[j]=h; ll[j]=l;
    }
    const size_t o = tb + (size_t)oct*1024 + row*8;
    *reinterpret_cast<half8*>(&oh[o]) = hh;
    if (ol) *reinterpret_cast<half8*>(&ol[o]) = ll;
  }
}

// ---------------- fp16x2 pair-GEMM (prologue, packed operands, 4-buf counted pipeline) ----
__global__ __launch_bounds__(256)
void pairgemm_k(const _Float16* __restrict__ Ahg, const _Float16* __restrict__ Alg,
                const _Float16* __restrict__ Bhg, const _Float16* __restrict__ Blg,
                float* __restrict__ partial, int N, int K, int kzn,
                const int* __restrict__ guard)
{
  if (guard[0]) return;
  __shared__ _Float16 lds[4][8192];
  const int t = (int)threadIdx.x;
  const int lane = t & 63, wid = t >> 6;
  const int wr = wid >> 1, wc = wid & 1;
  const int ln = lane & 31, lg = lane >> 5;

  const int nt = (int)blockIdx.x, mt = (int)blockIdx.y, kz = (int)blockIdx.z;
  const int m0 = mt*128, n0 = nt*128;
  const int chunk = (3*K)/kzn;
  const int loExt = kz*chunk;
  const int nsteps = chunk/32;
  int ss = (2*K - loExt)/32;
  const int scaleStep = ss < 0 ? 0 : ss;
  const int KT = K >> 5;

  f32x16 acc[2][2];
  #pragma unroll
  for (int fm=0;fm<2;fm++)
    #pragma unroll
    for (int fn=0;fn<2;fn++)
      #pragma unroll
      for (int r=0;r<16;r++) acc[fm][fn][r] = 0.f;

  auto stage = [&](int i, int buf){
    const int gext = loExt + i*32;
    const _Float16* aB; const _Float16* bB; int kk;
    if (gext < K)         { aB = Ahg; bB = Blg; kk = gext; }
    else if (gext < 2*K)  { aB = Alg; bB = Bhg; kk = gext - K; }
    else                  { aB = Ahg; bB = Bhg; kk = gext - 2*K; }
    const int kt = kk >> 5;
    const _Float16* aT = aB + ((size_t)(mt*KT + kt))*4096;
    const _Float16* bT = bB + ((size_t)((n0>>7)*KT + kt))*4096;
    _Float16* base = &lds[buf][0];
    #pragma unroll
    for (int q=0;q<2;q++){
      const int W = q*4 + wid;
      __builtin_amdgcn_global_load_lds(
        (const __attribute__((address_space(1))) void*)(aT + W*512 + lane*8),
        (__attribute__((address_space(3))) void*)(base + W*512), 16, 0, 0);
      __builtin_amdgcn_global_load_lds(
        (const __attribute__((address_space(1))) void*)(bT + W*512 + lane*8),
        (__attribute__((address_space(3))) void*)(base + 4096 + W*512), 16, 0, 0);
    }
  };

  asm volatile("s_waitcnt vmcnt(0)" ::: "memory");
  stage(0, 0);
  if (nsteps > 1) stage(1, 1);
  if (nsteps > 2) stage(2, 2);

  for (int i=0; i<nsteps; ++i){
    if (i+2 < nsteps)      asm volatile("s_waitcnt vmcnt(8)" ::: "memory");
    else if (i+1 < nsteps) asm volatile("s_waitcnt vmcnt(4)" ::: "memory");
    else                   asm volatile("s_waitcnt vmcnt(0)" ::: "memory");
    __builtin_amdgcn_sched_barrier(0);
    __builtin_amdgcn_s_barrier();
    __builtin_amdgcn_sched_barrier(0);
    if (i+3 < nsteps) stage(i+3, (i+3)&3);
    const _Float16* As = &lds[i&3][0];
    const _Float16* Bs = &lds[i&3][4096];
    half8 a[2][2], b[2][2];
    #pragma unroll
    for (int fm=0; fm<2; ++fm){
      const int row = wr*64 + fm*32 + ln;
      #pragma unroll
      for (int ks=0; ks<2; ++ks)
        a[fm][ks] = *reinterpret_cast<const half8*>(&As[(ks*2+lg)*1024 + row*8]);
    }
    #pragma unroll
    for (int fn=0; fn<2; ++fn){
      const int row = wc*64 + fn*32 + ln;
      #pragma unroll
      for (int ks=0; ks<2; ++ks)
        b[fn][ks] = *reinterpret_cast<const half8*>(&Bs[(ks*2+lg)*1024 + row*8]);
    }
    if (i == scaleStep){
      #pragma unroll
      for (int fm=0;fm<2;fm++)
        #pragma unroll
        for (int fn=0;fn<2;fn++)
          #pragma unroll
          for (int r=0;r<16;r++) acc[fm][fn][r] *= INV2048;
    }
    __builtin_amdgcn_s_setprio(1);
    #pragma unroll
    for (int ks=0; ks<2; ++ks)
      #pragma unroll
      for (int fm=0; fm<2; ++fm)
        #pragma unroll
        for (int fn=0; fn<2; ++fn)
          acc[fm][fn] = __builtin_amdgcn_mfma_f32_32x32x16_f16(a[fm][ks], b[fn][ks], acc[fm][fn], 0, 0, 0);
    __builtin_amdgcn_s_setprio(0);
  }
  if (scaleStep >= nsteps){
    #pragma unroll
    for (int fm=0;fm<2;fm++)
      #pragma unroll
      for (int fn=0;fn<2;fn++)
        #pragma unroll
        for (int r=0;r<16;r++) acc[fm][fn][r] *= INV2048;
  }

  float* __restrict__ dst = partial + (size_t)kz*BSZ*N;
  #pragma unroll
  for (int fm=0; fm<2; ++fm)
    #pragma unroll
    for (int fn=0; fn<2; ++fn)
      #pragma unroll
      for (int r=0; r<16; ++r){
        const int row = (r&3) + 8*(r>>2) + 4*lg;
        const int gm = m0 + wr*64 + fm*32 + row;
        const int gn = n0 + wc*64 + fn*32 + ln;
        dst[(size_t)gm*N + gn] = acc[fm][fn][r];
      }
}

// sum of kz partials + f32 epilogue. grid (N/256, 16)
__global__ __launch_bounds__(256)
void sumn_k(const float* __restrict__ partial, int ng, int N,
            const float* __restrict__ bvec, const float* __restrict__ subm,
            int relu, float* __restrict__ outf, const int* __restrict__ guard)
{
  if (guard && guard[0]) return;
  const int c = blockIdx.x*256 + threadIdx.x;
  const int rb = blockIdx.y;
  const size_t SZ = (size_t)BSZ*N;
  for (int r=0; r<16; ++r){
    const size_t idx = (size_t)(rb*16+r)*N + c;
    float s = 0.f;
    for (int g=0; g<ng; ++g) s += partial[(size_t)g*SZ + idx];
    if (bvec) s += bvec[c];
    if (subm) s -= subm[idx];
    if (relu) s = fmaxf(s, 0.f);
    outf[idx] = s;
  }
}

// ---------------- fused loop MFMA kernel: packed, 3-segment single-acc,
// 4-buffer 3-deep counted-vmcnt pipeline + setprio ----------------
__global__ __launch_bounds__(256)
void fusedm_k(const _Float16* __restrict__ Ahg, const _Float16* __restrict__ Alg,
              const _Float16* __restrict__ Wzh, const _Float16* __restrict__ Wzl,
              const _Float16* __restrict__ Wbt,
              float* __restrict__ pp, float* __restrict__ ppe,
              int projKz, int eqKz, const int* __restrict__ guard)
{
  if (guard[0]) return;
  __shared__ _Float16 lds[4][8192];
  const int t = (int)threadIdx.x;
  const int lane = t & 63, wid = t >> 6;
  const int wr = wid >> 1, wc = wid & 1;
  const int ln = lane & 31, lg = lane >> 5;

  const int nwg = (int)gridDim.x;
  const int hw = (int)blockIdx.x;
  const int L = (hw & 7)*(nwg >> 3) + (hw >> 3);

  const int nProj = 64*projKz;
  const bool is_eq = L >= nProj;
  int kz, mt, nt, nsteps, scaleStep, loExt = 0, kbase = 0;
  if (!is_eq){
    mt = L & 1;
    kz = (L >> 1) % projKz;
    nt = L / (2*projKz);
    const int chunk = 12288 / projKz;
    loExt = kz * chunk;
    nsteps = chunk / 32;
    const int ss = (8192 - loExt) / 32;
    scaleStep = ss < 0 ? 0 : ss;
  } else {
    const int E = L - nProj;
    mt = E & 1;
    kz = (E >> 1) % eqKz;
    nt = E / (2*eqKz);
    nsteps = (NV/eqKz) / 32;
    kbase = kz*(NV/eqKz);
    scaleStep = -1;
  }
  const int m0 = mt*128, n0 = nt*128;
  const int KT = NV >> 5;

  f32x16 acc[2][2];
  #pragma unroll
  for (int fm=0;fm<2;fm++)
    #pragma unroll
    for (int fn=0;fn<2;fn++)
      #pragma unroll
      for (int r=0;r<16;r++) acc[fm][fn][r] = 0.f;

  auto stage = [&](int i, int buf){
    const _Float16 *aB, *bB; int kk;
    if (is_eq){
      aB = Ahg; bB = Wbt; kk = kbase + i*32;
    } else {
      const int gext = loExt + i*32;
      if (gext < 4096)      { aB = Ahg; bB = Wzl; kk = gext; }
      else if (gext < 8192) { aB = Alg; bB = Wzh; kk = gext - 4096; }
      else                  { aB = Ahg; bB = Wzh; kk = gext - 8192; }
    }
    const int kt = kk >> 5;
    const _Float16* aT = aB + ((size_t)(mt*KT + kt))*4096;
    const _Float16* bT = bB + ((size_t)((n0>>7)*KT + kt))*4096;
    _Float16* base = &lds[buf][0];
    #pragma unroll
    for (int q=0;q<2;q++){
      const int W = q*4 + wid;
      __builtin_amdgcn_global_load_lds(
        (const __attribute__((address_space(1))) void*)(aT + W*512 + lane*8),
        (__attribute__((address_space(3))) void*)(base + W*512), 16, 0, 0);
      __builtin_amdgcn_global_load_lds(
        (const __attribute__((address_space(1))) void*)(bT + W*512 + lane*8),
        (__attribute__((address_space(3))) void*)(base + 4096 + W*512), 16, 0, 0);
    }
  };

  // drain guard load, then prime 3-deep
  asm volatile("s_waitcnt vmcnt(0)" ::: "memory");
  stage(0, 0);
  if (nsteps > 1) stage(1, 1);
  if (nsteps > 2) stage(2, 2);

  for (int i=0; i<nsteps; ++i){
    if (i+2 < nsteps)      asm volatile("s_waitcnt vmcnt(8)" ::: "memory");
    else if (i+1 < nsteps) asm volatile("s_waitcnt vmcnt(4)" ::: "memory");
    else                   asm volatile("s_waitcnt vmcnt(0)" ::: "memory");
    __builtin_amdgcn_sched_barrier(0);
    __builtin_amdgcn_s_barrier();          // stage(i) landed everywhere; step i-1 reads done
    __builtin_amdgcn_sched_barrier(0);
    if (i+3 < nsteps) stage(i+3, (i+3)&3); // overwrites buf[(i-1)&3], readers finished
    const _Float16* As = &lds[i&3][0];
    const _Float16* Bs = &lds[i&3][4096];
    half8 a[2][2], b[2][2];
    #pragma unroll
    for (int fm=0; fm<2; ++fm){
      const int row = wr*64 + fm*32 + ln;
      #pragma unroll
      for (int ks=0; ks<2; ++ks)
        a[fm][ks] = *reinterpret_cast<const half8*>(&As[(ks*2+lg)*1024 + row*8]);
    }
    #pragma unroll
    for (int fn=0; fn<2; ++fn){
      const int row = wc*64 + fn*32 + ln;
      #pragma unroll
      for (int ks=0; ks<2; ++ks)
        b[fn][ks] = *reinterpret_cast<const half8*>(&Bs[(ks*2+lg)*1024 + row*8]);
    }
    if (!is_eq && i == scaleStep){
      #pragma unroll
      for (int fm=0;fm<2;fm++)
        #pragma unroll
        for (int fn=0;fn<2;fn++)
          #pragma unroll
          for (int r=0;r<16;r++) acc[fm][fn][r] *= INV2048;
    }
    __builtin_amdgcn_s_setprio(1);
    #pragma unroll
    for (int ks=0; ks<2; ++ks)
      #pragma unroll
      for (int fm=0; fm<2; ++fm)
        #pragma unroll
        for (int fn=0; fn<2; ++fn)
          acc[fm][fn] = __builtin_amdgcn_mfma_f32_32x32x16_f16(a[fm][ks], b[fn][ks], acc[fm][fn], 0, 0, 0);
    __builtin_amdgcn_s_setprio(0);
  }
  if (!is_eq && scaleStep >= nsteps){
    #pragma unroll
    for (int fm=0;fm<2;fm++)
      #pragma unroll
      for (int fn=0;fn<2;fn++)
        #pragma unroll
        for (int r=0;r<16;r++) acc[fm][fn][r] *= INV2048;
  }

  if (is_eq){
    float* __restrict__ dst = ppe + (size_t)kz*BSZ*MC;
    #pragma unroll
    for (int fm=0; fm<2; ++fm)
      #pragma unroll
      for (int fn=0; fn<2; ++fn)
        #pragma unroll
        for (int r=0; r<16; ++r){
          const int row = (r&3) + 8*(r>>2) + 4*lg;
          const int gm = m0 + wr*64 + fm*32 + row;
          const int gn = n0 + wc*64 + fn*32 + ln;
          dst[(size_t)gm*MC + gn] = acc[fm][fn][r];
        }
  } else {
    float* __restrict__ dst = pp + (size_t)kz*BSZ*NV;
    #pragma unroll
    for (int fm=0; fm<2; ++fm)
      #pragma unroll
      for (int fn=0; fn<2; ++fn)
        #pragma unroll
        for (int r=0; r<16; ++r){
          const int row = (r&3) + 8*(r>>2) + 4*lg;
          const int gm = m0 + wr*64 + fm*32 + row;
          const int gn = n0 + wc*64 + fn*32 + ln;
          dst[(size_t)gm*NV + gn] = acc[fm][fn][r];
        }
  }
}

// combine + ineq + relu-split-pack (coalesced). grid = (BSZ/128)*(NV/32)
__global__ __launch_bounds__(256)
void combinep_k(const float* __restrict__ pp, int ng, const float* __restrict__ BiasM,
                float* __restrict__ zout, _Float16* __restrict__ rzh,
                _Float16* __restrict__ rzl, float* __restrict__ ineqpart,
                const int* __restrict__ guard)
{
  if (guard[0]) return;
  __shared__ float ts[128][33];
  const int t = (int)threadIdx.x;
  const int bid = (int)blockIdx.x;
  const int rt = bid >> 7, kt = bid & 127;
  const size_t SZ = (size_t)BSZ*NV;
  #pragma unroll
  for (int p=0;p<4;p++){
    const int row = p*32 + (t>>3);
    const int c4 = (t&7)*4;
    const size_t idx = (size_t)(rt*128+row)*NV + kt*32 + c4;
    float4 z = *reinterpret_cast<const float4*>(&BiasM[idx]);
    for (int g=0; g<ng; ++g){
      const float4 v = *reinterpret_cast<const float4*>(&pp[(size_t)g*SZ + idx]);
      z.x+=v.x; z.y+=v.y; z.z+=v.z; z.w+=v.w;
    }
    *reinterpret_cast<float4*>(&zout[idx]) = z;
    ts[row][c4+0]=z.x; ts[row][c4+1]=z.y; ts[row][c4+2]=z.z; ts[row][c4+3]=z.w;
  }
  __syncthreads();
  {
    const int g = t >> 5, c = t & 31;
    float s = 0.f;
    #pragma unroll
    for (int r=0;r<16;r++) s += fmaxf(-ts[g*16+r][c], 0.f);
    ineqpart[(size_t)(rt*8+g)*NV + kt*32 + c] = s;
  }
  const bool rl = (kt*32 >= FREEN);
  const int oct = t >> 6;
  const size_t tb = (size_t)bid*4096;
  #pragma unroll
  for (int rr=0; rr<2; ++rr){
    const int row = (t&63)*2 + rr;
    half8 hh, ll;
    #pragma unroll
    for (int j=0;j<8;j++){
      float v = ts[row][oct*8+j];
      if (rl) v = fmaxf(v, 0.f);
      _Float16 h,l; split_f32(v,h,l); hh[j]=h; ll[j]=l;
    }
    const size_t o = tb + (size_t)oct*1024 + row*8;
    *reinterpret_cast<half8*>(&rzh[o]) = hh;
    *reinterpret_cast<half8*>(&rzl[o]) = ll;
  }
}

__global__ __launch_bounds__(256)
void eqredN_k(const float* __restrict__ ppe, const float* __restrict__ BiasATmB,
              float* __restrict__ eqpart16, int ng, const int* __restrict__ guard)
{
  if (guard[0]) return;
  const int c = blockIdx.x*256 + threadIdx.x;
  const int rb = blockIdx.y;
  const size_t SE = (size_t)BSZ*MC;
  float s = 0.f;
  for (int r=0; r<16; ++r){
    const size_t idx = (size_t)(rb*16+r)*MC + c;
    float acc = 0.f;
    for (int g=0; g<ng; ++g) acc += ppe[(size_t)g*SE + idx];
    s += fabsf(BiasATmB[idx] + EPSF*acc);
  }
  eqpart16[(size_t)rb*MC + c] = s;
}

__global__ __launch_bounds__(256)
void check3_k(const float* __restrict__ eqpart16, const float* __restrict__ ineqpart,
              int* __restrict__ viol, const int* __restrict__ done)
{
  if (done[0]) return;
  const int id = blockIdx.x*256 + threadIdx.x;
  bool bad;
  if (id < MC){
    float s = 0.f;
    #pragma unroll
    for (int g=0; g<16; g++) s += eqpart16[(size_t)g*MC + id];
    bad = (s*(1.f/(float)BSZ) > TOLF);
  } else {
    const int c = FREEN + (id - MC);
    float s = 0.f;
    #pragma unroll
    for (int g=0; g<16; g++) s += ineqpart[(size_t)g*NV + c];
    bad = (s*(1.f/(float)BSZ) > TOLF);
  }
  if (bad) atomicAdd(viol, 1);
}

// ---------------- LayerNorm ----------------
__global__ __launch_bounds__(256)
void ln_k(float* __restrict__ x, const float* __restrict__ g, const float* __restrict__ b)
{
  const int row = blockIdx.x, t = threadIdx.x;
  float4 v = *reinterpret_cast<const float4*>(&x[(size_t)row*HID + t*4]);
  __shared__ float sm[256];
  sm[t] = v.x+v.y+v.z+v.w;
  __syncthreads();
  for (int st=128; st>0; st>>=1){ if (t<st) sm[t]+=sm[t+st]; __syncthreads(); }
  const float mu = sm[0]*(1.f/(float)HID);
  __syncthreads();
  const float dx=v.x-mu, dy=v.y-mu, dz=v.z-mu, dw=v.w-mu;
  sm[t] = dx*dx+dy*dy+dz*dz+dw*dw;
  __syncthreads();
  for (int st=128; st>0; st>>=1){ if (t<st) sm[t]+=sm[t+st]; __syncthreads(); }
  const float inv = 1.f/sqrtf(sm[0]*(1.f/(float)HID) + 1e-5f);
  const int c = t*4;
  const float4 gv = *reinterpret_cast<const float4*>(&g[c]);
  const float4 bv = *reinterpret_cast<const float4*>(&b[c]);
  float4 o;
  o.x = dx*inv*gv.x + bv.x; o.y = dy*inv*gv.y + bv.y;
  o.z = dz*inv*gv.z + bv.z; o.w = dw*inv*gv.w + bv.w;
  *reinterpret_cast<float4*>(&x[(size_t)row*HID + c]) = o;
}

// ---------------- flags / fallback machinery ----------------
__global__ __launch_bounds__(256)
void check_k(const float* __restrict__ eqpart, const float* __restrict__ znew,
             int* __restrict__ viol, const int* __restrict__ done, int ngroups)
{
  if (done[0]) return;
  const int id = blockIdx.x*256 + threadIdx.x;
  bool bad;
  if (id < MC){
    float s = 0.f;
    for (int g=0; g<ngroups; g++) s += eqpart[g*MC + id];
    bad = (s*(1.f/(float)BSZ) > TOLF);
  } else {
    const int c = FREEN + (id - MC);
    float s = 0.f;
    for (int r=0; r<BSZ; r++){
      const float v = znew[(size_t)r*NV + c];
      s += (v < 0.f) ? -v : 0.f;
    }
    bad = (s*(1.f/(float)BSZ) > TOLF);
  }
  if (bad) atomicAdd(viol, 1);
}

__global__ void init_k(int* flags){ flags[0]=0; flags[1]=0; flags[2]=0; }

__global__ void update_k(int* flags){
  if (!flags[0]){ flags[1] += 1; if (flags[2]==0) flags[0]=1; }
  flags[2] = 0;
}

__global__ __launch_bounds__(256)
void final_k(const float* __restrict__ buf1, float* __restrict__ out, const int* __restrict__ flags)
{
  const int i = blockIdx.x*256 + threadIdx.x;
  const int k = flags[1];
  if ((k & 1) && i < BSZ*NV) out[i] = buf1[i];
  if (i == 0) out[2*BSZ*NV] = (float)k;
}

__global__ void finalp_k(float* __restrict__ out, const int* __restrict__ flags)
{
  out[2*(size_t)BSZ*NV] = (float)flags[1];
}

// ---------------- host launch ----------------
extern "C" void kernel_launch(void* const* d_in, const int* in_sizes, int n_in,
                              void* d_out, int out_size, void* d_ws, size_t ws_size,
                              hipStream_t stream)
{
  const float* bp  = (const float*)d_in[0];
  const float* w1  = (const float*)d_in[1];
  const float* b1  = (const float*)d_in[2];
  const float* g1  = (const float*)d_in[3];
  const float* be1 = (const float*)d_in[4];
  const float* w2  = (const float*)d_in[5];
  const float* b2  = (const float*)d_in[6];
  const float* g2  = (const float*)d_in[7];
  const float* be2 = (const float*)d_in[8];
  const float* w3  = (const float*)d_in[9];
  const float* b3  = (const float*)d_in[10];
  const float* g3  = (const float*)d_in[11];
  const float* be3 = (const float*)d_in[12];
  const float* wo  = (const float*)d_in[13];
  const float* bo  = (const float*)d_in[14];
  const float* A   = (const float*)d_in[15];
  const float* Wz  = (const float*)d_in[16];
  const float* Wb  = (const float*)d_in[17];

  float* out  = (float*)d_out;
  float* z0   = out + (size_t)BSZ*NV;
  float* zbuf = out;

  auto layout_need = [&](int PKZ_, int EKZ_)->size_t{
    size_t f = (size_t)1048576*(1+PKZ_) + (size_t)524288*EKZ_ + 524288 + 32768 + 65536 + 16;
    size_t h = (size_t)NV*NV*2 + (size_t)MC*NV + (size_t)2*BSZ*NV;
    return f*4 + h*2;
  };
  int PKZ = 6, EKZ = 4;
  if (ws_size < layout_need(6,4)) { PKZ = 4; EKZ = 2; }
  const bool fp16path = (ws_size >= layout_need(PKZ, EKZ));
  const int KZBIG = (PKZ == 6) ? 6 : 4;   // prologue kz (pp holds PKZ partials)

  float* ws_f = (float*)d_ws;
  float* BiasM    = ws_f;
  float* pp       = BiasM + (size_t)BSZ*NV;
  float* ppe      = pp + (size_t)PKZ*BSZ*NV;
  float* BiasATmB = ppe + (size_t)EKZ*BSZ*MC;
  float* eqpart16 = BiasATmB + (size_t)BSZ*MC;
  float* ineqpart = eqpart16 + (size_t)16*MC;
  int*   flags    = (int*)(ineqpart + (size_t)16*NV);
  _Float16* Wzh = (_Float16*)(flags + 16);
  _Float16* Wzl = Wzh + (size_t)NV*NV;
  _Float16* Wbt = Wzl + (size_t)NV*NV;
  _Float16* rzh = Wbt + (size_t)MC*NV;
  _Float16* rzl = rzh + (size_t)BSZ*NV;

  _Float16* PBh = Wzh;
  _Float16* PBl = Wzh + (size_t)NV*NV/2;
  _Float16* bph = Wzl;
  _Float16* bpl = bph + (size_t)BSZ*MC;
  float*    hbuf = (float*)(bpl + (size_t)BSZ*MC);
  _Float16* hph = (_Float16*)(hbuf + (size_t)BSZ*HID);
  _Float16* hpl = hph + (size_t)BSZ*HID;
  _Float16* Bsh = hpl + (size_t)BSZ*HID;
  _Float16* Bsl = Bsh + (size_t)BSZ*NV;
  _Float16* zh0 = rzh;
  _Float16* zl0 = rzl;

  const dim3 blk(256);

  if (fp16path){
    hipLaunchKernelGGL(init_k, dim3(1), dim3(1), 0, stream, flags);

    // ---- MLP via pair-MFMA (packed operands) ----
    hipLaunchKernelGGL((packpair_k<false>), dim3((BSZ/128)*(MC/32)), blk, 0, stream, bp, bph, bpl, BSZ, MC, nullptr);
    hipLaunchKernelGGL(trpackpair_k, dim3((HID/128)*(MC/32)), blk, 0, stream, w1, PBh, PBl, MC, HID);
    hipLaunchKernelGGL(pairgemm_k, dim3(HID/128, 2, KZBIG), blk, 0, stream, bph, bpl, PBh, PBl, pp, HID, MC, KZBIG, flags);
    hipLaunchKernelGGL(sumn_k, dim3(HID/256, 16), blk, 0, stream, pp, KZBIG, HID, b1, nullptr, 1, hbuf, flags);
    hipLaunchKernelGGL(ln_k, dim3(BSZ), blk, 0, stream, hbuf, g1, be1);
    hipLaunchKernelGGL((packpair_k<false>), dim3((BSZ/128)*(HID/32)), blk, 0, stream, hbuf, hph, hpl, BSZ, HID, nullptr);

    hipLaunchKernelGGL(trpackpair_k, dim3((HID/128)*(HID/32)), blk, 0, stream, w2, PBh, PBl, HID, HID);
    hipLaunchKernelGGL(pairgemm_k, dim3(HID/128, 2, KZBIG), blk, 0, stream, hph, hpl, PBh, PBl, pp, HID, HID, KZBIG, flags);
    hipLaunchKernelGGL(sumn_k, dim3(HID/256, 16), blk, 0, stream, pp, KZBIG, HID, b2, nullptr, 1, hbuf, flags);
    hipLaunchKernelGGL(ln_k, dim3(BSZ), blk, 0, stream, hbuf, g2, be2);
    hipLaunchKernelGGL((packpair_k<false>), dim3((BSZ/128)*(HID/32)), blk, 0, stream, hbuf, hph, hpl, BSZ, HID, nullptr);

    hipLaunchKernelGGL(trpackpair_k, dim3((HID/128)*(HID/32)), blk, 0, stream, w3, PBh, PBl, HID, HID);
    hipLaunchKernelGGL(pairgemm_k, dim3(HID/128, 2, KZBIG), blk, 0, stream, hph, hpl, PBh, PBl, pp, HID, HID, KZBIG, flags);
    hipLaunchKernelGGL(sumn_k, dim3(HID/256, 16), blk, 0, stream, pp, KZBIG, HID, b3, nullptr, 1, hbuf, flags);
    hipLaunchKernelGGL(ln_k, dim3(BSZ), blk, 0, stream, hbuf, g3, be3);
    hipLaunchKernelGGL((packpair_k<false>), dim3((BSZ/128)*(HID/32)), blk, 0, stream, hbuf, hph, hpl, BSZ, HID, nullptr);

    // z0 = h3 @ wo + bo
    hipLaunchKernelGGL(trpackpair_k, dim3((NV/128)*(HID/32)), blk, 0, stream, wo, PBh, PBl, HID, NV);
    hipLaunchKernelGGL(pairgemm_k, dim3(NV/128, 2, KZBIG), blk, 0, stream, hph, hpl, PBh, PBl, pp, NV, HID, KZBIG, flags);
    hipLaunchKernelGGL(sumn_k, dim3(NV/256, 16), blk, 0, stream, pp, KZBIG, NV, bo, nullptr, 0, z0, flags);
    hipLaunchKernelGGL((packpair_k<false>), dim3((BSZ/128)*(NV/32)), blk, 0, stream, z0, zh0, zl0, BSZ, NV, nullptr);

    // Bias = bp @ WbProj^T
    hipLaunchKernelGGL((packpair_k<false>), dim3((NV/128)*(MC/32)), blk, 0, stream, Wb, PBh, PBl, NV, MC, nullptr);
    hipLaunchKernelGGL(pairgemm_k, dim3(NV/128, 2, KZBIG), blk, 0, stream, bph, bpl, PBh, PBl, pp, NV, MC, KZBIG, flags);
    hipLaunchKernelGGL(sumn_k, dim3(NV/256, 16), blk, 0, stream, pp, KZBIG, NV, nullptr, nullptr, 0, BiasM, flags);
    hipLaunchKernelGGL((packpair_k<false>), dim3((BSZ/128)*(NV/32)), blk, 0, stream, BiasM, Bsh, Bsl, BSZ, NV, nullptr);

    // BiasATmB = Bias @ A^T - bp
    hipLaunchKernelGGL((packpair_k<false>), dim3((MC/128)*(NV/32)), blk, 0, stream, A, PBh, PBl, MC, NV, nullptr);
    hipLaunchKernelGGL(pairgemm_k, dim3(MC/128, 2, KZBIG), blk, 0, stream, Bsh, Bsl, PBh, PBl, pp, MC, NV, KZBIG, flags);
    hipLaunchKernelGGL(sumn_k, dim3(MC/256, 16), blk, 0, stream, pp, KZBIG, MC, nullptr, bp, 0, BiasATmB, flags);

    // loop constants
    hipLaunchKernelGGL(trpackpair_k, dim3((MC/128)*(NV/32)), blk, 0, stream, Wb, Wbt, (_Float16*)nullptr, NV, MC);
    hipLaunchKernelGGL((packpair_k<false>), dim3((NV/128)*(NV/32)), blk, 0, stream, Wz, Wzh, Wzl, NV, NV, nullptr);

    // bootstrap: z_init = Bias + z0 @ Wp (proj blocks only)
    hipLaunchKernelGGL(fusedm_k, dim3(64*PKZ), blk, 0, stream,
                       zh0, zl0, Wzh, Wzl, Wbt, pp, ppe, PKZ, 1, flags);
    hipLaunchKernelGGL(combinep_k, dim3((BSZ/128)*(NV/32)), blk, 0, stream,
                       pp, PKZ, BiasM, zbuf, rzh, rzl, ineqpart, flags);

    const int loopGrid = 64*PKZ + 32*EKZ;
    for (int j=1; j<=NITER; ++j){
      hipLaunchKernelGGL(fusedm_k, dim3(loopGrid), blk, 0, stream,
                         rzh, rzl, Wzh, Wzl, Wbt, pp, ppe, PKZ, EKZ, flags);
      hipLaunchKernelGGL(combinep_k, dim3((BSZ/128)*(NV/32)), blk, 0, stream,
                         pp, PKZ, BiasM, zbuf, rzh, rzl, ineqpart, flags);
      hipLaunchKernelGGL(eqredN_k, dim3(MC/256, 16), blk, 0, stream,
                         ppe, BiasATmB, eqpart16, EKZ, flags);
      hipLaunchKernelGGL(check3_k, dim3((MC + (NV-FREEN))/256), blk, 0, stream,
                         eqpart16, ineqpart, flags+2, flags);
      hipLaunchKernelGGL(update_k, dim3(1), dim3(1), 0, stream, flags);
    }
    hipLaunchKernelGGL(finalp_k, dim3(1), dim3(1), 0, stream, out, flags);
  } else {
    // fallback: proven f32 loop
    float* ftmp1 = ws_f;
    float* ftmp2 = ftmp1 + (size_t)BSZ*HID;
    float* fBias = ftmp2 + (size_t)BSZ*HID;
    float* fbuf1 = fBias + (size_t)BSZ*NV;
    float* feqp  = fbuf1 + (size_t)BSZ*NV;
    int*   ffl   = (int*)(feqp + 8*MC);

    hipLaunchKernelGGL(init_k, dim3(1), dim3(1), 0, stream, ffl);
    hipLaunchKernelGGL((gemm_k<64,64,32,4,4,false,false,EPI_BIASRELU>), dim3(HID/64, BSZ/64), blk, 0, stream,
                       bp, MC, w1, HID, ftmp1, MC, HID, b1, nullptr, 0, nullptr);
    hipLaunchKernelGGL(ln_k, dim3(BSZ), blk, 0, stream, ftmp1, g1, be1);
    hipLaunchKernelGGL((gemm_k<64,64,32,4,4,false,false,EPI_BIASRELU>), dim3(HID/64, BSZ/64), blk, 0, stream,
                       ftmp1, HID, w2, HID, ftmp2, HID, HID, b2, nullptr, 0, nullptr);
    hipLaunchKernelGGL(ln_k, dim3(BSZ), blk, 0, stream, ftmp2, g2, be2);
    hipLaunchKernelGGL((gemm_k<64,64,32,4,4,false,false,EPI_BIASRELU>), dim3(HID/64, BSZ/64), blk, 0, stream,
                       ftmp2, HID, w3, HID, ftmp1, HID, HID, b3, nullptr, 0, nullptr);
    hipLaunchKernelGGL(ln_k, dim3(BSZ), blk, 0, stream, ftmp1, g3, be3);
    hipLaunchKernelGGL((gemm_k<64,64,32,4,4,false,false,EPI_BIAS>), dim3(NV/64, BSZ/64), blk, 0, stream,
                       ftmp1, HID, wo, NV, z0, HID, NV, bo, nullptr, 0, nullptr);
    hipLaunchKernelGGL((gemm_k<64,64,32,4,4,true,false,EPI_NONE>), dim3(NV/64, BSZ/64), blk, 0, stream,
                       bp, MC, Wb, MC, fBias, MC, NV, nullptr, nullptr, 0, nullptr);
    hipLaunchKernelGGL((gemm_k<64,64,32,4,4,true,false,EPI_ADDMAT>), dim3(NV/64, BSZ/64), blk, 0, stream,
                       z0, NV, Wz, NV, out, NV, NV, nullptr, fBias, NV, nullptr);
    for (int j=1; j<=NITER; ++j){
      float* src = (j&1) ? out : fbuf1;
      float* dst = (j&1) ? fbuf1 : out;
      hipLaunchKernelGGL((gemm_k<64,64,32,4,4,true,true,EPI_ADDMAT>), dim3(NV/64, BSZ/64), blk, 0, stream,
                         src, NV, Wz, NV, dst, NV, NV, nullptr, fBias, NV, ffl);
      hipLaunchKernelGGL((gemm_k<32,64,32,2,4,true,false,EPI_EQ>), dim3(MC/64, BSZ/32), blk, 0, stream,
                         dst, NV, A, NV, feqp, NV, MC, nullptr, bp, MC, ffl);
      hipLaunchKernelGGL(check_k, dim3((MC + (NV-FREEN))/256), blk, 0, stream, feqp, dst, ffl+2, ffl, 8);
      hipLaunchKernelGGL(update_k, dim3(1), dim3(1), 0, stream, ffl);
    }
    hipLaunchKernelGGL(final_k, dim3((BSZ*NV)/256), blk, 0, stream, fbuf1, out, ffl);
  }

  (void)in_sizes; (void)n_in; (void)out_size; (void)ws_size;
}